// Round 1
// baseline (15172.839 us; speedup 1.0000x reference)
//
#include <hip/hip_runtime.h>
#include <math.h>

#define CDIV(a,b) (((a)+(b)-1)/(b))

// ---------------------------------------------------------------- copy
__global__ __launch_bounds__(256) void copy_kernel(float* __restrict__ dst,
                                                   const float* __restrict__ src, int n) {
  int i = blockIdx.x*256 + threadIdx.x;
  if (i < n) dst[i] = src[i];
}

__global__ __launch_bounds__(256) void add_kernel(float* __restrict__ x,
                                                  const float* __restrict__ y, int n) {
  int i = blockIdx.x*256 + threadIdx.x;
  if (i < n) x[i] += y[i];
}

// ---------------------------------------------------------------- LayerNorm over last dim C
__global__ __launch_bounds__(256) void ln_kernel(const float* __restrict__ in,
    const float* __restrict__ g, const float* __restrict__ b,
    float* __restrict__ out, int C, float eps)
{
  int t = blockIdx.x;
  const float* row = in + (size_t)t*C;
  float s = 0.f, s2 = 0.f;
  for (int c = threadIdx.x; c < C; c += 256) { float v = row[c]; s += v; s2 += v*v; }
  __shared__ float rs[256], rq[256];
  rs[threadIdx.x] = s; rq[threadIdx.x] = s2;
  __syncthreads();
  for (int off = 128; off > 0; off >>= 1) {
    if (threadIdx.x < off) { rs[threadIdx.x] += rs[threadIdx.x+off]; rq[threadIdx.x] += rq[threadIdx.x+off]; }
    __syncthreads();
  }
  float mean = rs[0] / C;
  float var  = rq[0] / C - mean*mean;
  float inv  = rsqrtf(var + eps);
  float* orow = out + (size_t)t*C;
  for (int c = threadIdx.x; c < C; c += 256)
    orow[c] = (row[c]-mean)*inv*g[c] + b[c];
}

// ---------------------------------------------------------------- window partition 64x64 -> 25 windows of 14x14 (zero pad)
__global__ __launch_bounds__(256) void winpart_kernel(const float* __restrict__ in,
                                                      float* __restrict__ out) {
  int i = blockIdx.x*256 + threadIdx.x;          // out index [25*196*768]
  if (i >= 25*196*768) return;
  int c = i % 768; int t = (i / 768) % 196; int b = i / (768*196);
  int wy = b / 5, wx = b % 5;
  int iy = t / 14, ix = t % 14;
  int h = wy*14 + iy, w = wx*14 + ix;
  out[i] = (h < 64 && w < 64) ? in[((size_t)(h*64 + w))*768 + c] : 0.f;
}

// window unpartition (crop pad) + residual add into x
__global__ __launch_bounds__(256) void unpart_add_kernel(float* __restrict__ x,
                                                         const float* __restrict__ p) {
  int i = blockIdx.x*256 + threadIdx.x;          // x index [4096*768]
  if (i >= 4096*768) return;
  int c = i % 768; int hw = i / 768; int w = hw % 64; int h = hw / 64;
  int wy = h/14, iy = h%14, wx = w/14, ix = w%14;
  int b = wy*5 + wx; int t = iy*14 + ix;
  x[i] += p[((size_t)(b*196 + t))*768 + c];
}

// ---------------------------------------------------------------- generic fp32 GEMM: C = act(A@B + bias) (+ res)
// A [M,K] row-major, B [K,N] row-major. N % 128 == 0, K % 8 == 0. act: 0 none, 1 exact GELU.
__global__ __launch_bounds__(256) void gemm_kernel(const float* __restrict__ A,
    const float* __restrict__ Bm, const float* __restrict__ bias,
    const float* __restrict__ res, float* __restrict__ C,
    int M, int N, int K, int act)
{
  __shared__ float As[8][132];
  __shared__ float Bs[8][132];
  int tid = threadIdx.x;
  int tcol = tid & 15, trow = tid >> 4;
  int rowBase = blockIdx.y*128, colBase = blockIdx.x*128;
  float acc[8][8] = {};
  for (int k0 = 0; k0 < K; k0 += 8) {
    #pragma unroll
    for (int i = 0; i < 4; ++i) {
      int idx = i*256 + tid;
      int r  = idx >> 3,  c  = idx & 7;      // A tile: [128 rows][8 k]
      int gr = rowBase + r;
      As[c][r] = (gr < M) ? A[(size_t)gr*K + k0 + c] : 0.f;
      int rb = idx >> 7, cb = idx & 127;     // B tile: [8 k][128 cols]
      Bs[rb][cb] = Bm[(size_t)(k0+rb)*N + colBase + cb];
    }
    __syncthreads();
    #pragma unroll
    for (int kk = 0; kk < 8; ++kk) {
      float a[8], bb[8];
      #pragma unroll
      for (int i=0;i<8;++i) a[i]  = As[kk][trow*8+i];
      #pragma unroll
      for (int j=0;j<8;++j) bb[j] = Bs[kk][tcol*8+j];
      #pragma unroll
      for (int i=0;i<8;++i)
        #pragma unroll
        for (int j=0;j<8;++j)
          acc[i][j] = fmaf(a[i], bb[j], acc[i][j]);
    }
    __syncthreads();
  }
  #pragma unroll
  for (int i=0;i<8;++i) {
    int gr = rowBase + trow*8 + i;
    if (gr >= M) continue;
    #pragma unroll
    for (int j=0;j<8;++j) {
      int gc = colBase + tcol*8 + j;
      float v = acc[i][j];
      if (bias) v += bias[gc];
      if (act == 1) v = 0.5f*v*(1.f + erff(v*0.70710678118f));
      if (res) v += res[(size_t)gr*N + gc];
      C[(size_t)gr*N + gc] = v;
    }
  }
}

// ---------------------------------------------------------------- decomposed rel-pos bias
// out[((b*12+n)*T + t)*S + kk] = dot(q[b,n,t,:], table[coord - kk + S - 1, :])
// coord = t/S (useH) or t%S (useW). q is the q slice of the fused qkv buffer (stride 2304).
__global__ __launch_bounds__(256) void relbias_kernel(const float* __restrict__ qkv,
    const float* __restrict__ table, float* __restrict__ out,
    int nWin, int T, int S, int useH)
{
  int gid = blockIdx.x*256 + threadIdx.x;
  int total = nWin*12*T*S;
  if (gid >= total) return;
  int kk = gid % S; int r = gid / S;
  int t = r % T; int r2 = r / T; int n = r2 % 12; int b = r2 / 12;
  int coord = useH ? (t / S) : (t % S);
  const float* q  = qkv + ((size_t)(b*T + t))*2304 + n*64;
  const float* tb = table + (size_t)(coord - kk + S - 1)*64;
  float s0=0.f, s1=0.f;
  #pragma unroll
  for (int d=0; d<64; d+=2) { s0 = fmaf(q[d], tb[d], s0); s1 = fmaf(q[d+1], tb[d+1], s1); }
  out[gid] = s0 + s1;
}

// ---------------------------------------------------------------- attention (online softmax, 1 thread per (win, head, query))
// qkv layout per token row (stride 2304): [q | k | v], each 12 heads x 64.
__global__ __launch_bounds__(256) void attn_kernel(const float* __restrict__ qkv,
    const float* __restrict__ rh, const float* __restrict__ rw,
    float* __restrict__ out, int nWin, int T, int S)
{
  int gid = blockIdx.x*256 + threadIdx.x;
  int total = nWin*12*T;
  if (gid >= total) return;
  int t = gid % T; int n = (gid / T) % 12; int b = gid / (12*T);
  const float* qrow = qkv + ((size_t)(b*T + t))*2304 + n*64;
  float q[64];
  #pragma unroll
  for (int d=0; d<64; ++d) q[d] = qrow[d];
  const float* rhp = rh + ((size_t)((b*12+n)*T + t))*S;
  const float* rwp = rw + ((size_t)((b*12+n)*T + t))*S;
  float m = -1e30f, l = 0.f;
  float acc[64];
  #pragma unroll
  for (int d=0; d<64; ++d) acc[d] = 0.f;
  const float* kbase = qkv + (size_t)b*T*2304 + 768  + n*64;
  const float* vbase = qkv + (size_t)b*T*2304 + 1536 + n*64;
  for (int k=0; k<T; ++k) {
    const float* kr = kbase + (size_t)k*2304;
    float s0=0.f,s1=0.f,s2=0.f,s3=0.f;
    #pragma unroll
    for (int d=0; d<64; d+=4) {
      s0 = fmaf(q[d],   kr[d],   s0);
      s1 = fmaf(q[d+1], kr[d+1], s1);
      s2 = fmaf(q[d+2], kr[d+2], s2);
      s3 = fmaf(q[d+3], kr[d+3], s3);
    }
    int kh = k / S, kw = k - kh*S;
    float s = (s0+s1+s2+s3)*0.125f + rhp[kh] + rwp[kw];
    float mn = fmaxf(m, s);
    float corr = __expf(m - mn);
    float p    = __expf(s - mn);
    l = l*corr + p;
    const float* vr = vbase + (size_t)k*2304;
    #pragma unroll
    for (int d=0; d<64; ++d) acc[d] = fmaf(acc[d], corr, p*vr[d]);
    m = mn;
  }
  float inv = 1.f / l;
  float* orow = out + ((size_t)(b*T + t))*768 + n*64;
  #pragma unroll
  for (int d=0; d<64; ++d) orow[d] = acc[d]*inv;
}

// ---------------------------------------------------------------- 3x3 conv SAME, NHWC 64x64x256 -> 64x64x256, HWIO weights
__global__ __launch_bounds__(256) void conv3_kernel(const float* __restrict__ in,
    const float* __restrict__ w, float* __restrict__ out)
{
  int gid = blockIdx.x*256 + threadIdx.x;
  if (gid >= 64*64*256) return;
  int co = gid & 255; int p = gid >> 8; int x = p & 63; int y = p >> 6;
  float s0 = 0.f, s1 = 0.f;
  for (int dy=0; dy<3; ++dy) {
    int yy = y + dy - 1; if (yy < 0 || yy >= 64) continue;
    for (int dx=0; dx<3; ++dx) {
      int xx = x + dx - 1; if (xx < 0 || xx >= 64) continue;
      const float* ip = in + (size_t)(yy*64 + xx)*256;
      const float* wp = w + (size_t)((dy*3 + dx)*256)*256 + co;
      for (int ci=0; ci<256; ci+=2) {
        s0 = fmaf(ip[ci],   wp[(size_t)ci*256],       s0);
        s1 = fmaf(ip[ci+1], wp[(size_t)(ci+1)*256],   s1);
      }
    }
  }
  out[gid] = s0 + s1;
}

// ---------------------------------------------------------------- NHWC -> NCHW
__global__ __launch_bounds__(256) void nchw_kernel(const float* __restrict__ in,
                                                   float* __restrict__ out) {
  int gid = blockIdx.x*256 + threadIdx.x;   // out index: (c*64+h)*64+w
  if (gid >= 256*64*64) return;
  int w = gid & 63; int h = (gid >> 6) & 63; int c = gid >> 12;
  out[gid] = in[(size_t)(h*64 + w)*256 + c];
}

// ================================================================ launch
extern "C" void kernel_launch(void* const* d_in, const int* in_sizes, int n_in,
                              void* d_out, int out_size, void* d_ws, size_t ws_size,
                              hipStream_t stream)
{
  const float* x_in   = (const float*)d_in[0];
  const float* ln1_g  = (const float*)d_in[1];
  const float* ln1_b  = (const float*)d_in[2];
  const float* qkv_w  = (const float*)d_in[3];
  const float* qkv_b  = (const float*)d_in[4];
  const float* proj_w = (const float*)d_in[5];
  const float* proj_b = (const float*)d_in[6];
  const float* rel_h  = (const float*)d_in[7];
  const float* rel_w  = (const float*)d_in[8];
  const float* ln2_g  = (const float*)d_in[9];
  const float* ln2_b  = (const float*)d_in[10];
  const float* fc1_w  = (const float*)d_in[11];
  const float* fc1_b  = (const float*)d_in[12];
  const float* fc2_w  = (const float*)d_in[13];
  const float* fc2_b  = (const float*)d_in[14];
  const float* nconv1 = (const float*)d_in[15];
  const float* nln1_g = (const float*)d_in[16];
  const float* nln1_b = (const float*)d_in[17];
  const float* nconv2 = (const float*)d_in[18];
  const float* nln2_g = (const float*)d_in[19];
  const float* nln2_b = (const float*)d_in[20];

  // workspace layout (floats). bufQ (qkv, 11.29M) and bufE (mlp hidden, 12.58M)
  // are never simultaneously live -> share one 12.58M region.
  float* ws    = (float*)d_ws;
  float* xbuf  = ws;                 // 4096*768   = 3,145,728
  float* bufC  = xbuf  + 3145728;    // 4900*768   = 3,763,200
  float* bufD  = bufC  + 3763200;    // 4900*768   = 3,763,200
  float* bufQE = bufD  + 3763200;    // max(4900*2304, 4096*3072) = 12,582,912
  float* bufRH = bufQE + 12582912;   // 12*4096*64 = 3,145,728
  float* bufRW = bufRH + 3145728;    // 3,145,728
  // total = 29,546,496 floats = 118.2 MB

  copy_kernel<<<CDIV(3145728,256),256,0,stream>>>(xbuf, x_in, 3145728);

  for (int i = 0; i < 4; ++i) {
    int wsz = (i < 3) ? 14 : 0;
    ln_kernel<<<4096,256,0,stream>>>(xbuf, ln1_g + i*768, ln1_b + i*768, bufC, 768, 1e-5f);
    int M, nWin, T, S;
    const float* qkvIn;
    if (wsz > 0) {
      winpart_kernel<<<CDIV(25*196*768,256),256,0,stream>>>(bufC, bufD);
      qkvIn = bufD; M = 4900; nWin = 25; T = 196; S = 14;
    } else {
      qkvIn = bufC; M = 4096; nWin = 1; T = 4096; S = 64;
    }
    gemm_kernel<<<dim3(2304/128, CDIV(M,128)),256,0,stream>>>(
        qkvIn, qkv_w + (size_t)i*768*2304, qkv_b + i*2304, nullptr, bufQE, M, 2304, 768, 0);
    int relTot = nWin*12*T*S;
    relbias_kernel<<<CDIV(relTot,256),256,0,stream>>>(bufQE, rel_h + i*127*64, bufRH, nWin, T, S, 1);
    relbias_kernel<<<CDIV(relTot,256),256,0,stream>>>(bufQE, rel_w + i*127*64, bufRW, nWin, T, S, 0);
    int aTot = nWin*12*T;
    attn_kernel<<<CDIV(aTot,256),256,0,stream>>>(bufQE, bufRH, bufRW, bufC, nWin, T, S);
    gemm_kernel<<<dim3(768/128, CDIV(M,128)),256,0,stream>>>(
        bufC, proj_w + (size_t)i*768*768, proj_b + i*768, nullptr, bufD, M, 768, 768, 0);
    if (wsz > 0)
      unpart_add_kernel<<<CDIV(3145728,256),256,0,stream>>>(xbuf, bufD);
    else
      add_kernel<<<CDIV(3145728,256),256,0,stream>>>(xbuf, bufD, 3145728);
    // MLP
    ln_kernel<<<4096,256,0,stream>>>(xbuf, ln2_g + i*768, ln2_b + i*768, bufC, 768, 1e-5f);
    gemm_kernel<<<dim3(3072/128, 4096/128),256,0,stream>>>(
        bufC, fc1_w + (size_t)i*768*3072, fc1_b + i*3072, nullptr, bufQE, 4096, 3072, 768, 1);
    gemm_kernel<<<dim3(768/128, 4096/128),256,0,stream>>>(
        bufQE, fc2_w + (size_t)i*3072*768, fc2_b + i*768, xbuf, xbuf, 4096, 768, 3072, 0);
  }

  // neck
  gemm_kernel<<<dim3(256/128, 4096/128),256,0,stream>>>(
      xbuf, nconv1, nullptr, nullptr, bufC, 4096, 256, 768, 0);
  ln_kernel<<<4096,256,0,stream>>>(bufC, nln1_g, nln1_b, bufD, 256, 1e-6f);
  conv3_kernel<<<CDIV(64*64*256,256),256,0,stream>>>(bufD, nconv2, bufC);
  ln_kernel<<<4096,256,0,stream>>>(bufC, nln2_g, nln2_b, bufD, 256, 1e-6f);
  nchw_kernel<<<CDIV(1048576,256),256,0,stream>>>(bufD, (float*)d_out);
}

// Round 2
// 4308.670 us; speedup vs baseline: 3.5215x; 3.5215x over previous
//
#include <hip/hip_runtime.h>
#include <math.h>

#define CDIV(a,b) (((a)+(b)-1)/(b))

typedef __attribute__((ext_vector_type(8))) short short8v;   // 8 bf16 = 4 VGPRs
typedef __attribute__((ext_vector_type(4))) float float4v;

__device__ __forceinline__ ushort f2b(float f) {
  union { float f; unsigned u; } v; v.f = f;
  unsigned r = (v.u + 0x7fffu + ((v.u >> 16) & 1u)) >> 16;   // RNE
  return (ushort)r;
}
__device__ __forceinline__ float b2f(ushort h) {
  union { unsigned u; float f; } v; v.u = ((unsigned)h) << 16;
  return v.f;
}

// ---------------------------------------------------------------- elementwise
__global__ __launch_bounds__(256) void copy_kernel(float* __restrict__ dst,
                                                   const float* __restrict__ src, int n) {
  int i = blockIdx.x*256 + threadIdx.x;
  if (i < n) dst[i] = src[i];
}

__global__ __launch_bounds__(256) void cvt_kernel(const float* __restrict__ in,
                                                  ushort* __restrict__ out, int n) {
  int i = blockIdx.x*256 + threadIdx.x;
  if (i < n) out[i] = f2b(in[i]);
}

// ---------------------------------------------------------------- LayerNorm (optionally bf16 out)
__global__ __launch_bounds__(256) void ln_kernel(const float* __restrict__ in,
    const float* __restrict__ g, const float* __restrict__ b,
    float* __restrict__ outf, ushort* __restrict__ outb, int C, float eps)
{
  int t = blockIdx.x;
  const float* row = in + (size_t)t*C;
  float s = 0.f, s2 = 0.f;
  for (int c = threadIdx.x; c < C; c += 256) { float v = row[c]; s += v; s2 += v*v; }
  __shared__ float rs[256], rq[256];
  rs[threadIdx.x] = s; rq[threadIdx.x] = s2;
  __syncthreads();
  for (int off = 128; off > 0; off >>= 1) {
    if (threadIdx.x < off) { rs[threadIdx.x] += rs[threadIdx.x+off]; rq[threadIdx.x] += rq[threadIdx.x+off]; }
    __syncthreads();
  }
  float mean = rs[0] / C;
  float var  = rq[0] / C - mean*mean;
  float inv  = rsqrtf(var + eps);
  for (int c = threadIdx.x; c < C; c += 256) {
    float v = (row[c]-mean)*inv*g[c] + b[c];
    if (outb) outb[(size_t)t*C + c] = f2b(v);
    else      outf[(size_t)t*C + c] = v;
  }
}

// ---------------------------------------------------------------- window partition (bf16)
__global__ __launch_bounds__(256) void winpart_kernel(const ushort* __restrict__ in,
                                                      ushort* __restrict__ out) {
  int i = blockIdx.x*256 + threadIdx.x;          // out index [25*196*768]
  if (i >= 25*196*768) return;
  int c = i % 768; int t = (i / 768) % 196; int b = i / (768*196);
  int wy = b / 5, wx = b % 5;
  int iy = t / 14, ix = t % 14;
  int h = wy*14 + iy, w = wx*14 + ix;
  out[i] = (h < 64 && w < 64) ? in[((size_t)(h*64 + w))*768 + c] : (ushort)0;
}

__global__ __launch_bounds__(256) void unpart_add_kernel(float* __restrict__ x,
                                                         const float* __restrict__ p) {
  int i = blockIdx.x*256 + threadIdx.x;          // x index [4096*768]
  if (i >= 4096*768) return;
  int c = i % 768; int hw = i / 768; int w = hw % 64; int h = hw / 64;
  int wy = h/14, iy = h%14, wx = w/14, ix = w%14;
  int b = wy*5 + wx; int t = iy*14 + ix;
  x[i] += p[((size_t)(b*196 + t))*768 + c];
}

__global__ __launch_bounds__(256) void add_kernel(float* __restrict__ x,
                                                  const float* __restrict__ y, int n) {
  int i = blockIdx.x*256 + threadIdx.x;
  if (i < n) x[i] += y[i];
}

// ---------------------------------------------------------------- weight transpose+convert: in [K][N] f32 -> out [N][K] bf16
__global__ __launch_bounds__(256) void transpose_cvt_kernel(const float* __restrict__ in,
    ushort* __restrict__ out, int K, int N)
{
  __shared__ float t[32][33];
  int n0 = blockIdx.x*32, k0 = blockIdx.y*32;
  int cc = threadIdx.x & 31, rr = threadIdx.x >> 5;
  for (int r = rr; r < 32; r += 8) t[r][cc] = in[(size_t)(k0+r)*N + n0 + cc];
  __syncthreads();
  for (int r = rr; r < 32; r += 8) out[(size_t)(n0+r)*K + k0 + cc] = f2b(t[cc][r]);
}

// ---------------------------------------------------------------- bf16 MFMA GEMM
// A [M][K] bf16, Bt [N][K] bf16 (weights transposed). Out: Cf fp32 or Cb bf16.
// 128x128 tile, BK=32, 4 waves (2x2), each wave 4x4 16x16x32 mfma frags.
__global__ __launch_bounds__(256) void gemm_bf16_kernel(
    const ushort* __restrict__ A, const ushort* __restrict__ Bt,
    const float* __restrict__ bias, const float* __restrict__ res,
    float* __restrict__ Cf, ushort* __restrict__ Cb,
    int M, int N, int K, int act)
{
  __shared__ ushort Al[128*40];   // row stride 40 shorts (80 B) -> 2-way bank alias (free)
  __shared__ ushort Bl[128*40];
  int tid = threadIdx.x;
  int lane = tid & 63, wave = tid >> 6;
  int wm = wave & 1, wn = wave >> 1;
  int l15 = lane & 15, lq = lane >> 4;
  int rowBase = blockIdx.y * 128, colBase = blockIdx.x * 128;
  float4v acc[4][4];
  #pragma unroll
  for (int i=0;i<4;++i)
    #pragma unroll
    for (int j=0;j<4;++j) acc[i][j] = (float4v){0.f,0.f,0.f,0.f};

  int sRow = tid >> 1;            // 0..127
  int sCol = (tid & 1) << 4;      // 0 / 16 elements
  int aRow = rowBase + sRow;
  bool aval = aRow < M;
  const ushort* aP = A  + (size_t)(aval ? aRow : 0) * K + sCol;
  const ushort* bP = Bt + (size_t)(colBase + sRow) * K + sCol;
  ushort* aL = Al + sRow*40 + sCol;
  ushort* bL = Bl + sRow*40 + sCol;
  uint4 z4 = {0u,0u,0u,0u};

  for (int k0 = 0; k0 < K; k0 += 32) {
    uint4 a0 = aval ? *(const uint4*)(aP + k0)     : z4;
    uint4 a1 = aval ? *(const uint4*)(aP + k0 + 8) : z4;
    uint4 b0 = *(const uint4*)(bP + k0);
    uint4 b1 = *(const uint4*)(bP + k0 + 8);
    __syncthreads();
    *(uint4*)aL = a0; *(uint4*)(aL + 8) = a1;
    *(uint4*)bL = b0; *(uint4*)(bL + 8) = b1;
    __syncthreads();
    short8v af[4], bf[4];
    #pragma unroll
    for (int mi=0; mi<4; ++mi)
      af[mi] = *(const short8v*)(Al + (wm*64 + mi*16 + l15)*40 + lq*8);
    #pragma unroll
    for (int ni=0; ni<4; ++ni)
      bf[ni] = *(const short8v*)(Bl + (wn*64 + ni*16 + l15)*40 + lq*8);
    #pragma unroll
    for (int mi=0; mi<4; ++mi)
      #pragma unroll
      for (int ni=0; ni<4; ++ni)
        acc[mi][ni] = __builtin_amdgcn_mfma_f32_16x16x32_bf16(af[mi], bf[ni], acc[mi][ni], 0, 0, 0);
  }
  #pragma unroll
  for (int mi=0; mi<4; ++mi) {
    int gr0 = rowBase + wm*64 + mi*16 + lq*4;
    #pragma unroll
    for (int ni=0; ni<4; ++ni) {
      int gc = colBase + wn*64 + ni*16 + l15;
      float bsv = bias ? bias[gc] : 0.f;
      #pragma unroll
      for (int r=0; r<4; ++r) {
        int gr = gr0 + r;
        if (gr < M) {
          float v = acc[mi][ni][r] + bsv;
          if (act) v = 0.5f*v*(1.f + erff(v*0.70710678118f));
          if (res) v += res[(size_t)gr*N + gc];
          if (Cf) Cf[(size_t)gr*N + gc] = v;
          else    Cb[(size_t)gr*N + gc] = f2b(v);
        }
      }
    }
  }
}

// ---------------------------------------------------------------- decomposed rel-pos bias (bf16 out)
__global__ __launch_bounds__(256) void relbias_kernel(const float* __restrict__ qkv,
    const float* __restrict__ table, ushort* __restrict__ out,
    int nWin, int T, int S, int useH)
{
  int gid = blockIdx.x*256 + threadIdx.x;
  int total = nWin*12*T*S;
  if (gid >= total) return;
  int kk = gid % S; int r = gid / S;
  int t = r % T; int r2 = r / T; int n = r2 % 12; int b = r2 / 12;
  int coord = useH ? (t / S) : (t % S);
  const float* q  = qkv + ((size_t)(b*T + t))*2304 + n*64;
  const float* tb = table + (size_t)(coord - kk + S - 1)*64;
  float s0=0.f, s1=0.f;
  #pragma unroll
  for (int d=0; d<64; d+=2) { s0 = fmaf(q[d], tb[d], s0); s1 = fmaf(q[d+1], tb[d+1], s1); }
  out[gid] = f2b(s0 + s1);
}

// ---------------------------------------------------------------- attention v2
// block = (q-tile of 64, head, win); 4 waves = 4 key chunks of L=T/4 each.
// K/V staged in LDS (16 keys/chunk per stage), inner reads are wave-broadcast.
template<int S>
__global__ __launch_bounds__(256) void attn2_kernel(
    const float* __restrict__ qkv, const ushort* __restrict__ rh,
    const ushort* __restrict__ rw, ushort* __restrict__ outb,
    int T, int L)
{
  __shared__ float Kl[64][64];
  __shared__ float Vl[64][64];
  __shared__ float mlbuf[128];
  int qt = blockIdx.x, n = blockIdx.y, b = blockIdx.z;
  int tid = threadIdx.x, lane = tid & 63, c = tid >> 6;
  int q = qt*64 + lane;
  bool qv = q < T;
  int qc = qv ? q : 0;
  const float* qrow = qkv + ((size_t)(b*T + qc))*2304 + n*64;
  float qreg[64];
  #pragma unroll
  for (int d4 = 0; d4 < 16; ++d4) *(float4*)(qreg + 4*d4) = *(const float4*)(qrow + 4*d4);
  const ushort* rhp = rh + ((size_t)((b*12+n)*T + qc))*S;
  const ushort* rwp = rw + ((size_t)((b*12+n)*T + qc))*S;
  float m = -1e30f, l = 0.f;
  float acc[64];
  #pragma unroll
  for (int d=0; d<64; ++d) acc[d] = 0.f;

  int sr  = tid >> 2;           // staged row 0..63
  int scc = sr >> 4;            // which chunk this staged row belongs to
  int sj  = sr & 15;
  int sc4 = (tid & 3) << 4;     // col offset 0/16/32/48
  const float* kbase = qkv + ((size_t)b)*T*2304 + 768 + n*64 + sc4;

  for (int i0 = 0; i0 < L; i0 += 16) {
    int skey = scc*L + i0 + sj;
    bool skv = (i0 + sj) < L;
    const float* kr = kbase + (size_t)(skv ? skey : 0)*2304;
    float4 kz = {0.f,0.f,0.f,0.f};
    #pragma unroll
    for (int u=0; u<4; ++u) {
      float4 kvv = skv ? *(const float4*)(kr + 4*u)       : kz;
      float4 vvv = skv ? *(const float4*)(kr + 768 + 4*u) : kz;
      *(float4*)(&Kl[sr][sc4 + 4*u]) = kvv;
      *(float4*)(&Vl[sr][sc4 + 4*u]) = vvv;
    }
    __syncthreads();
    int jmax = L - i0; if (jmax > 16) jmax = 16;
    for (int j = 0; j < jmax; ++j) {
      int key = c*L + i0 + j;
      const float* kp = Kl[c*16 + j];
      float s0=0.f,s1=0.f,s2=0.f,s3=0.f;
      #pragma unroll
      for (int d4=0; d4<16; ++d4) {
        float4 k4 = *(const float4*)(kp + 4*d4);
        s0 = fmaf(qreg[4*d4],   k4.x, s0);
        s1 = fmaf(qreg[4*d4+1], k4.y, s1);
        s2 = fmaf(qreg[4*d4+2], k4.z, s2);
        s3 = fmaf(qreg[4*d4+3], k4.w, s3);
      }
      int kh = key / S, kw = key - kh*S;
      float s = (s0+s1+s2+s3)*0.125f + b2f(rhp[kh]) + b2f(rwp[kw]);
      float mn = fmaxf(m, s);
      float corr = __expf(m - mn);
      float p = __expf(s - mn);
      l = l*corr + p;
      const float* vp = Vl[c*16 + j];
      #pragma unroll
      for (int d=0; d<64; ++d) acc[d] = fmaf(acc[d], corr, p*vp[d]);
      m = mn;
    }
    __syncthreads();
  }
  // merge the 4 chunk states (m, l, acc[64]) into wave 0
  float* mb = &Kl[0][0];
  for (int r = 1; r < 4; ++r) {
    if (c == r) {
      #pragma unroll
      for (int d=0; d<64; ++d) mb[d*64 + lane] = acc[d];
      mlbuf[lane] = m; mlbuf[64 + lane] = l;
    }
    __syncthreads();
    if (c == 0) {
      float m2 = mlbuf[lane], l2 = mlbuf[64+lane];
      float mn = fmaxf(m, m2);
      float c1 = __expf(m - mn), c2 = __expf(m2 - mn);
      l = l*c1 + l2*c2;
      #pragma unroll
      for (int d=0; d<64; ++d) acc[d] = acc[d]*c1 + mb[d*64+lane]*c2;
      m = mn;
    }
    __syncthreads();
  }
  if (c == 0 && qv) {
    float inv = 1.f / l;
    ushort* orow = outb + ((size_t)(b*T + q))*768 + n*64;
    #pragma unroll
    for (int d=0; d<64; ++d) orow[d] = f2b(acc[d]*inv);
  }
}

// ---------------------------------------------------------------- 3x3 conv SAME, NHWC 64x64x256
__global__ __launch_bounds__(256) void conv3_kernel(const float* __restrict__ in,
    const float* __restrict__ w, float* __restrict__ out)
{
  int gid = blockIdx.x*256 + threadIdx.x;
  if (gid >= 64*64*256) return;
  int co = gid & 255; int p = gid >> 8; int x = p & 63; int y = p >> 6;
  float s0 = 0.f, s1 = 0.f;
  for (int dy=0; dy<3; ++dy) {
    int yy = y + dy - 1; if (yy < 0 || yy >= 64) continue;
    for (int dx=0; dx<3; ++dx) {
      int xx = x + dx - 1; if (xx < 0 || xx >= 64) continue;
      const float* ip = in + (size_t)(yy*64 + xx)*256;
      const float* wp = w + (size_t)((dy*3 + dx)*256)*256 + co;
      for (int ci=0; ci<256; ci+=2) {
        s0 = fmaf(ip[ci],   wp[(size_t)ci*256],     s0);
        s1 = fmaf(ip[ci+1], wp[(size_t)(ci+1)*256], s1);
      }
    }
  }
  out[gid] = s0 + s1;
}

__global__ __launch_bounds__(256) void nchw_kernel(const float* __restrict__ in,
                                                   float* __restrict__ out) {
  int gid = blockIdx.x*256 + threadIdx.x;
  if (gid >= 256*64*64) return;
  int w = gid & 63; int h = (gid >> 6) & 63; int c = gid >> 12;
  out[gid] = in[(size_t)(h*64 + w)*256 + c];
}

// ================================================================ launch
extern "C" void kernel_launch(void* const* d_in, const int* in_sizes, int n_in,
                              void* d_out, int out_size, void* d_ws, size_t ws_size,
                              hipStream_t stream)
{
  const float* x_in   = (const float*)d_in[0];
  const float* ln1_g  = (const float*)d_in[1];
  const float* ln1_b  = (const float*)d_in[2];
  const float* qkv_w  = (const float*)d_in[3];
  const float* qkv_b  = (const float*)d_in[4];
  const float* proj_w = (const float*)d_in[5];
  const float* proj_b = (const float*)d_in[6];
  const float* rel_h  = (const float*)d_in[7];
  const float* rel_w  = (const float*)d_in[8];
  const float* ln2_g  = (const float*)d_in[9];
  const float* ln2_b  = (const float*)d_in[10];
  const float* fc1_w  = (const float*)d_in[11];
  const float* fc1_b  = (const float*)d_in[12];
  const float* fc2_w  = (const float*)d_in[13];
  const float* fc2_b  = (const float*)d_in[14];
  const float* nconv1 = (const float*)d_in[15];
  const float* nln1_g = (const float*)d_in[16];
  const float* nln1_b = (const float*)d_in[17];
  const float* nconv2 = (const float*)d_in[18];
  const float* nln2_g = (const float*)d_in[19];
  const float* nln2_b = (const float*)d_in[20];

  // workspace layout (in floats, total 26,863,104 fl = 107.5 MB)
  float*  ws     = (float*)d_ws;
  float*  xbuf   = ws;                                   // 3,145,728 fl
  ushort* bufCs  = (ushort*)(xbuf + 3145728);            // 3,763,200 sh (1,881,600 fl)
  float*  bufD   = xbuf + 3145728 + 1881600;             // 3,763,200 fl
  float*  bufQE  = bufD + 3763200;                       // 11,289,600 fl (qkv f32 / mlp-hidden bf16)
  ushort* bufQEs = (ushort*)bufQE;
  ushort* rhB    = (ushort*)(bufQE + 11289600);          // 3,145,728 sh
  ushort* rwB    = rhB + 3145728;                        // 3,145,728 sh
  ushort* wqT    = rwB + 3145728;                        // 1,769,472 sh
  ushort* wpT    = wqT + 1769472;                        //   589,824 sh
  ushort* wf1T   = wpT + 589824;                         // 2,359,296 sh
  ushort* wf2T   = wf1T + 2359296;                       // 2,359,296 sh
  ushort* wnT    = wf2T + 2359296;                       //   196,608 sh
  ushort* bufDs  = (ushort*)bufD;

  copy_kernel<<<CDIV(3145728,256),256,0,stream>>>(xbuf, x_in, 3145728);

  for (int i = 0; i < 4; ++i) {
    int wsz = (i < 3) ? 14 : 0;
    // weight transpose+convert for this layer
    transpose_cvt_kernel<<<dim3(2304/32, 768/32),256,0,stream>>>(qkv_w + (size_t)i*768*2304, wqT, 768, 2304);
    transpose_cvt_kernel<<<dim3(768/32,  768/32),256,0,stream>>>(proj_w + (size_t)i*768*768,  wpT, 768, 768);
    transpose_cvt_kernel<<<dim3(3072/32, 768/32),256,0,stream>>>(fc1_w + (size_t)i*768*3072, wf1T, 768, 3072);
    transpose_cvt_kernel<<<dim3(768/32, 3072/32),256,0,stream>>>(fc2_w + (size_t)i*3072*768, wf2T, 3072, 768);

    ln_kernel<<<4096,256,0,stream>>>(xbuf, ln1_g + i*768, ln1_b + i*768, nullptr, bufCs, 768, 1e-5f);
    int M, nWin, T, S;
    const ushort* qkvIn;
    if (wsz > 0) {
      winpart_kernel<<<CDIV(25*196*768,256),256,0,stream>>>(bufCs, bufDs);
      qkvIn = bufDs; M = 4900; nWin = 25; T = 196; S = 14;
    } else {
      qkvIn = bufCs; M = 4096; nWin = 1; T = 4096; S = 64;
    }
    gemm_bf16_kernel<<<dim3(2304/128, CDIV(M,128)),256,0,stream>>>(
        qkvIn, wqT, qkv_b + i*2304, nullptr, bufQE, nullptr, M, 2304, 768, 0);
    int relTot = nWin*12*T*S;
    relbias_kernel<<<CDIV(relTot,256),256,0,stream>>>(bufQE, rel_h + i*127*64, rhB, nWin, T, S, 1);
    relbias_kernel<<<CDIV(relTot,256),256,0,stream>>>(bufQE, rel_w + i*127*64, rwB, nWin, T, S, 0);
    if (wsz > 0)
      attn2_kernel<14><<<dim3(CDIV(196,64),12,25),256,0,stream>>>(bufQE, rhB, rwB, bufCs, 196, 49);
    else
      attn2_kernel<64><<<dim3(64,12,1),256,0,stream>>>(bufQE, rhB, rwB, bufCs, 4096, 1024);
    gemm_bf16_kernel<<<dim3(768/128, CDIV(M,128)),256,0,stream>>>(
        bufCs, wpT, proj_b + i*768, nullptr, bufD, nullptr, M, 768, 768, 0);
    if (wsz > 0)
      unpart_add_kernel<<<CDIV(3145728,256),256,0,stream>>>(xbuf, bufD);
    else
      add_kernel<<<CDIV(3145728,256),256,0,stream>>>(xbuf, bufD, 3145728);
    // MLP
    ln_kernel<<<4096,256,0,stream>>>(xbuf, ln2_g + i*768, ln2_b + i*768, nullptr, bufCs, 768, 1e-5f);
    gemm_bf16_kernel<<<dim3(3072/128, 4096/128),256,0,stream>>>(
        bufCs, wf1T, fc1_b + i*3072, nullptr, nullptr, bufQEs, 4096, 3072, 768, 1);
    gemm_bf16_kernel<<<dim3(768/128, 4096/128),256,0,stream>>>(
        bufQEs, wf2T, fc2_b + i*768, xbuf, xbuf, nullptr, 4096, 768, 3072, 0);
  }

  // neck
  transpose_cvt_kernel<<<dim3(256/32, 768/32),256,0,stream>>>(nconv1, wnT, 768, 256);
  cvt_kernel<<<CDIV(3145728,256),256,0,stream>>>(xbuf, bufCs, 3145728);
  gemm_bf16_kernel<<<dim3(256/128, 4096/128),256,0,stream>>>(
      bufCs, wnT, nullptr, nullptr, bufD, nullptr, 4096, 256, 768, 0);
  ln_kernel<<<4096,256,0,stream>>>(bufD, nln1_g, nln1_b, bufQE, nullptr, 256, 1e-6f);
  conv3_kernel<<<CDIV(64*64*256,256),256,0,stream>>>(bufQE, nconv2, bufD);
  ln_kernel<<<4096,256,0,stream>>>(bufD, nln2_g, nln2_b, bufQE, nullptr, 256, 1e-6f);
  nchw_kernel<<<CDIV(1048576,256),256,0,stream>>>(bufQE, (float*)d_out);
}

// Round 3
// 2547.528 us; speedup vs baseline: 5.9559x; 1.6913x over previous
//
#include <hip/hip_runtime.h>
#include <math.h>

#define CDIV(a,b) (((a)+(b)-1)/(b))

typedef __attribute__((ext_vector_type(8))) short short8v;   // 8 bf16 = 4 VGPRs
typedef __attribute__((ext_vector_type(4))) float float4v;

__device__ __forceinline__ ushort f2b(float f) {
  union { float f; unsigned u; } v; v.f = f;
  unsigned r = (v.u + 0x7fffu + ((v.u >> 16) & 1u)) >> 16;   // RNE
  return (ushort)r;
}
__device__ __forceinline__ float b2f(ushort h) {
  union { unsigned u; float f; } v; v.u = ((unsigned)h) << 16;
  return v.f;
}

// ---------------------------------------------------------------- elementwise
__global__ __launch_bounds__(256) void copy_kernel(float* __restrict__ dst,
                                                   const float* __restrict__ src, int n) {
  int i = blockIdx.x*256 + threadIdx.x;
  if (i < n) dst[i] = src[i];
}

__global__ __launch_bounds__(256) void cvt_kernel(const float* __restrict__ in,
                                                  ushort* __restrict__ out, int n) {
  int i = blockIdx.x*256 + threadIdx.x;
  if (i < n) out[i] = f2b(in[i]);
}

// ---------------------------------------------------------------- LayerNorm (optionally bf16 out)
__global__ __launch_bounds__(256) void ln_kernel(const float* __restrict__ in,
    const float* __restrict__ g, const float* __restrict__ b,
    float* __restrict__ outf, ushort* __restrict__ outb, int C, float eps)
{
  int t = blockIdx.x;
  const float* row = in + (size_t)t*C;
  float s = 0.f, s2 = 0.f;
  for (int c = threadIdx.x; c < C; c += 256) { float v = row[c]; s += v; s2 += v*v; }
  __shared__ float rs[256], rq[256];
  rs[threadIdx.x] = s; rq[threadIdx.x] = s2;
  __syncthreads();
  for (int off = 128; off > 0; off >>= 1) {
    if (threadIdx.x < off) { rs[threadIdx.x] += rs[threadIdx.x+off]; rq[threadIdx.x] += rq[threadIdx.x+off]; }
    __syncthreads();
  }
  float mean = rs[0] / C;
  float var  = rq[0] / C - mean*mean;
  float inv  = rsqrtf(var + eps);
  for (int c = threadIdx.x; c < C; c += 256) {
    float v = (row[c]-mean)*inv*g[c] + b[c];
    if (outb) outb[(size_t)t*C + c] = f2b(v);
    else      outf[(size_t)t*C + c] = v;
  }
}

// ---------------------------------------------------------------- window partition (bf16)
__global__ __launch_bounds__(256) void winpart_kernel(const ushort* __restrict__ in,
                                                      ushort* __restrict__ out) {
  int i = blockIdx.x*256 + threadIdx.x;          // out index [25*196*768]
  if (i >= 25*196*768) return;
  int c = i % 768; int t = (i / 768) % 196; int b = i / (768*196);
  int wy = b / 5, wx = b % 5;
  int iy = t / 14, ix = t % 14;
  int h = wy*14 + iy, w = wx*14 + ix;
  out[i] = (h < 64 && w < 64) ? in[((size_t)(h*64 + w))*768 + c] : (ushort)0;
}

__global__ __launch_bounds__(256) void unpart_add_kernel(float* __restrict__ x,
                                                         const float* __restrict__ p) {
  int i = blockIdx.x*256 + threadIdx.x;          // x index [4096*768]
  if (i >= 4096*768) return;
  int c = i % 768; int hw = i / 768; int w = hw % 64; int h = hw / 64;
  int wy = h/14, iy = h%14, wx = w/14, ix = w%14;
  int b = wy*5 + wx; int t = iy*14 + ix;
  x[i] += p[((size_t)(b*196 + t))*768 + c];
}

__global__ __launch_bounds__(256) void add_kernel(float* __restrict__ x,
                                                  const float* __restrict__ y, int n) {
  int i = blockIdx.x*256 + threadIdx.x;
  if (i < n) x[i] += y[i];
}

// ---------------------------------------------------------------- weight transpose+convert: in [K][N] f32 -> out [N][K] bf16
__global__ __launch_bounds__(256) void transpose_cvt_kernel(const float* __restrict__ in,
    ushort* __restrict__ out, int K, int N)
{
  __shared__ float t[32][33];
  int n0 = blockIdx.x*32, k0 = blockIdx.y*32;
  int cc = threadIdx.x & 31, rr = threadIdx.x >> 5;
  for (int r = rr; r < 32; r += 8) t[r][cc] = in[(size_t)(k0+r)*N + n0 + cc];
  __syncthreads();
  for (int r = rr; r < 32; r += 8) out[(size_t)(n0+r)*K + k0 + cc] = f2b(t[cc][r]);
}

// ---------------------------------------------------------------- bf16 MFMA GEMM
// A [M][K] bf16, Bt [N][K] bf16 (weights transposed). Out: Cf fp32 or Cb bf16.
__global__ __launch_bounds__(256) void gemm_bf16_kernel(
    const ushort* __restrict__ A, const ushort* __restrict__ Bt,
    const float* __restrict__ bias, const float* __restrict__ res,
    float* __restrict__ Cf, ushort* __restrict__ Cb,
    int M, int N, int K, int act)
{
  __shared__ ushort Al[128*40];
  __shared__ ushort Bl[128*40];
  int tid = threadIdx.x;
  int lane = tid & 63, wave = tid >> 6;
  int wm = wave & 1, wn = wave >> 1;
  int l15 = lane & 15, lq = lane >> 4;
  int rowBase = blockIdx.y * 128, colBase = blockIdx.x * 128;
  float4v acc[4][4];
  #pragma unroll
  for (int i=0;i<4;++i)
    #pragma unroll
    for (int j=0;j<4;++j) acc[i][j] = (float4v){0.f,0.f,0.f,0.f};

  int sRow = tid >> 1;
  int sCol = (tid & 1) << 4;
  int aRow = rowBase + sRow;
  bool aval = aRow < M;
  const ushort* aP = A  + (size_t)(aval ? aRow : 0) * K + sCol;
  const ushort* bP = Bt + (size_t)(colBase + sRow) * K + sCol;
  ushort* aL = Al + sRow*40 + sCol;
  ushort* bL = Bl + sRow*40 + sCol;
  uint4 z4 = {0u,0u,0u,0u};

  for (int k0 = 0; k0 < K; k0 += 32) {
    uint4 a0 = aval ? *(const uint4*)(aP + k0)     : z4;
    uint4 a1 = aval ? *(const uint4*)(aP + k0 + 8) : z4;
    uint4 b0 = *(const uint4*)(bP + k0);
    uint4 b1 = *(const uint4*)(bP + k0 + 8);
    __syncthreads();
    *(uint4*)aL = a0; *(uint4*)(aL + 8) = a1;
    *(uint4*)bL = b0; *(uint4*)(bL + 8) = b1;
    __syncthreads();
    short8v af[4], bf[4];
    #pragma unroll
    for (int mi=0; mi<4; ++mi)
      af[mi] = *(const short8v*)(Al + (wm*64 + mi*16 + l15)*40 + lq*8);
    #pragma unroll
    for (int ni=0; ni<4; ++ni)
      bf[ni] = *(const short8v*)(Bl + (wn*64 + ni*16 + l15)*40 + lq*8);
    #pragma unroll
    for (int mi=0; mi<4; ++mi)
      #pragma unroll
      for (int ni=0; ni<4; ++ni)
        acc[mi][ni] = __builtin_amdgcn_mfma_f32_16x16x32_bf16(af[mi], bf[ni], acc[mi][ni], 0, 0, 0);
  }
  #pragma unroll
  for (int mi=0; mi<4; ++mi) {
    int gr0 = rowBase + wm*64 + mi*16 + lq*4;
    #pragma unroll
    for (int ni=0; ni<4; ++ni) {
      int gc = colBase + wn*64 + ni*16 + l15;
      float bsv = bias ? bias[gc] : 0.f;
      #pragma unroll
      for (int r=0; r<4; ++r) {
        int gr = gr0 + r;
        if (gr < M) {
          float v = acc[mi][ni][r] + bsv;
          if (act) v = 0.5f*v*(1.f + erff(v*0.70710678118f));
          if (res) v += res[(size_t)gr*N + gc];
          if (Cf) Cf[(size_t)gr*N + gc] = v;
          else    Cb[(size_t)gr*N + gc] = f2b(v);
        }
      }
    }
  }
}

// ---------------------------------------------------------------- decomposed rel-pos bias (bf16 qkv in, bf16 out)
__global__ __launch_bounds__(256) void relbias_kernel(const ushort* __restrict__ qkv,
    const float* __restrict__ table, ushort* __restrict__ out,
    int nWin, int T, int S, int useH)
{
  int gid = blockIdx.x*256 + threadIdx.x;
  int total = nWin*12*T*S;
  if (gid >= total) return;
  int kk = gid % S; int r = gid / S;
  int t = r % T; int r2 = r / T; int n = r2 % 12; int b = r2 / 12;
  int coord = useH ? (t / S) : (t % S);
  const ushort* q = qkv + ((size_t)(b*T + t))*2304 + n*64;
  const float* tb = table + (size_t)(coord - kk + S - 1)*64;
  float s0=0.f, s1=0.f;
  #pragma unroll
  for (int d=0; d<64; d+=2) { s0 = fmaf(b2f(q[d]), tb[d], s0); s1 = fmaf(b2f(q[d+1]), tb[d+1], s1); }
  out[gid] = f2b(s0 + s1);
}

// ---------------------------------------------------------------- MFMA flash attention
// Block = (64-query tile, head, window). 4 waves, each owns 16 q-rows.
// qkv bf16 [tok][2304] (q|k|v, 12 heads x 64). Loops 64-key tiles:
// S=Q@K^T (mfma) *0.125 + relbias, online softmax, P->LDS, O+=P@V (mfma).
template<int S>
__global__ __launch_bounds__(256) void attn3_kernel(
    const ushort* __restrict__ qkv, const ushort* __restrict__ rh,
    const ushort* __restrict__ rw, ushort* __restrict__ outb, int T)
{
  constexpr int SP = (S + 15) & ~15;
  __shared__ ushort Ql[64*72];    // stride 72 shorts: 36 dwords -> bank stagger
  __shared__ ushort Kl[64*72];
  __shared__ ushort Vt[64*72];    // V transposed [dim][key]
  __shared__ ushort Pl[64*72];
  __shared__ ushort RHl[64*SP];
  __shared__ ushort RWl[64*SP];

  int qt = blockIdx.x, n = blockIdx.y, b = blockIdx.z;
  int tid = threadIdx.x, lane = tid & 63, w = tid >> 6;
  int l15 = lane & 15, lq = lane >> 4;
  size_t tokBase = (size_t)b * T;
  int q0 = qt * 64;

  // stage Q tile + bias tables
  #pragma unroll
  for (int it = 0; it < 2; ++it) {
    int id = tid + it*256;                 // 0..511
    int r = id >> 3, ch = id & 7;
    int qq = q0 + r; if (qq >= T) qq = T - 1;
    *(uint4*)(Ql + r*72 + ch*8) =
        *(const uint4*)(qkv + (tokBase + qq)*2304 + n*64 + ch*8);
  }
  for (int idx = tid; idx < 64*S; idx += 256) {
    int r = idx / S, c = idx - r*S;
    int qq = q0 + r; if (qq >= T) qq = T - 1;
    size_t base = ((size_t)(b*12 + n)*T + qq)*S;
    RHl[r*SP + c] = rh[base + c];
    RWl[r*SP + c] = rw[base + c];
  }

  float m[4], l[4];
  #pragma unroll
  for (int r=0;r<4;++r){ m[r]=-1e30f; l[r]=0.f; }
  float4v O[4];
  #pragma unroll
  for (int i=0;i<4;++i) O[i] = (float4v){0.f,0.f,0.f,0.f};

  int nkt = (T + 63) >> 6;
  for (int kt = 0; kt < nkt; ++kt) {
    int k0 = kt*64;
    __syncthreads();
    // stage K (rows = keys)
    #pragma unroll
    for (int it=0; it<2; ++it) {
      int id = tid + it*256;
      int r = id >> 3, ch = id & 7;
      int kk = k0 + r; if (kk >= T) kk = T-1;
      *(uint4*)(Kl + r*72 + ch*8) =
        *(const uint4*)(qkv + (tokBase + kk)*2304 + 768 + n*64 + ch*8);
    }
    // stage V transposed
    #pragma unroll
    for (int it=0; it<2; ++it) {
      int id = tid + it*256;
      int key = id & 63, dch = id >> 6;    // dch 0..7
      int kk = k0 + key; if (kk >= T) kk = T-1;
      union { uint4 v; ushort u[8]; } tv;
      tv.v = *(const uint4*)(qkv + (tokBase + kk)*2304 + 1536 + n*64 + dch*8);
      #pragma unroll
      for (int u=0;u<8;++u) Vt[(dch*8+u)*72 + key] = tv.u[u];
    }
    __syncthreads();

    // QK^T for this wave's 16 q-rows
    short8v aq0 = *(const short8v*)(Ql + (w*16 + l15)*72 + lq*8);
    short8v aq1 = *(const short8v*)(Ql + (w*16 + l15)*72 + 32 + lq*8);
    float4v Sv[4];
    #pragma unroll
    for (int ni=0; ni<4; ++ni) {
      short8v bk0 = *(const short8v*)(Kl + (ni*16 + l15)*72 + lq*8);
      short8v bk1 = *(const short8v*)(Kl + (ni*16 + l15)*72 + 32 + lq*8);
      float4v s = (float4v){0.f,0.f,0.f,0.f};
      s = __builtin_amdgcn_mfma_f32_16x16x32_bf16(aq0, bk0, s, 0,0,0);
      s = __builtin_amdgcn_mfma_f32_16x16x32_bf16(aq1, bk1, s, 0,0,0);
      Sv[ni] = s;
    }

    // bias + mask + online softmax (C layout: row=lq*4+r, col=l15)
    float p[4][4];
    float alpha[4];
    #pragma unroll
    for (int r=0;r<4;++r) {
      int qlrow = w*16 + lq*4 + r;
      float sc[4];
      #pragma unroll
      for (int ni=0;ni<4;++ni) {
        int key = k0 + ni*16 + l15;
        int kcl = key < T ? key : 0;
        int kh = kcl / S, kw = kcl - kh*S;
        float v = Sv[ni][r]*0.125f + b2f(RHl[qlrow*SP+kh]) + b2f(RWl[qlrow*SP+kw]);
        sc[ni] = key < T ? v : -1e30f;
      }
      float mx = fmaxf(fmaxf(sc[0],sc[1]), fmaxf(sc[2],sc[3]));
      #pragma unroll
      for (int off=8; off>0; off>>=1) mx = fmaxf(mx, __shfl_xor(mx, off));
      float mn = fmaxf(m[r], mx);
      float al = __expf(m[r] - mn);
      m[r] = mn; alpha[r] = al;
      float rsum = 0.f;
      #pragma unroll
      for (int ni=0;ni<4;++ni) { float pv = __expf(sc[ni]-mn); p[ni][r] = pv; rsum += pv; }
      #pragma unroll
      for (int off=8; off>0; off>>=1) rsum += __shfl_xor(rsum, off);
      l[r] = l[r]*al + rsum;
    }
    #pragma unroll
    for (int ni=0;ni<4;++ni)
      #pragma unroll
      for (int r=0;r<4;++r)
        Pl[(w*16 + lq*4 + r)*72 + ni*16 + l15] = f2b(p[ni][r]);
    #pragma unroll
    for (int ni=0;ni<4;++ni)
      #pragma unroll
      for (int r=0;r<4;++r) O[ni][r] *= alpha[r];
    __syncthreads();   // P visible (intra-wave rows, but cheap & safe)

    // O += P@V
    short8v ap0 = *(const short8v*)(Pl + (w*16 + l15)*72 + lq*8);
    short8v ap1 = *(const short8v*)(Pl + (w*16 + l15)*72 + 32 + lq*8);
    #pragma unroll
    for (int ni=0;ni<4;++ni) {
      short8v bv0 = *(const short8v*)(Vt + (ni*16 + l15)*72 + lq*8);
      short8v bv1 = *(const short8v*)(Vt + (ni*16 + l15)*72 + 32 + lq*8);
      O[ni] = __builtin_amdgcn_mfma_f32_16x16x32_bf16(ap0, bv0, O[ni], 0,0,0);
      O[ni] = __builtin_amdgcn_mfma_f32_16x16x32_bf16(ap1, bv1, O[ni], 0,0,0);
    }
  }

  // epilogue: O / l -> out
  #pragma unroll
  for (int r=0;r<4;++r) {
    int qlrow = w*16 + lq*4 + r;
    int qg = q0 + qlrow;
    if (qg < T) {
      float inv = 1.f / l[r];
      #pragma unroll
      for (int ni=0;ni<4;++ni)
        outb[(tokBase + qg)*768 + n*64 + ni*16 + l15] = f2b(O[ni][r]*inv);
    }
  }
}

// ---------------------------------------------------------------- 3x3 conv SAME, NHWC 64x64x256
__global__ __launch_bounds__(256) void conv3_kernel(const float* __restrict__ in,
    const float* __restrict__ w, float* __restrict__ out)
{
  int gid = blockIdx.x*256 + threadIdx.x;
  if (gid >= 64*64*256) return;
  int co = gid & 255; int p = gid >> 8; int x = p & 63; int y = p >> 6;
  float s0 = 0.f, s1 = 0.f;
  for (int dy=0; dy<3; ++dy) {
    int yy = y + dy - 1; if (yy < 0 || yy >= 64) continue;
    for (int dx=0; dx<3; ++dx) {
      int xx = x + dx - 1; if (xx < 0 || xx >= 64) continue;
      const float* ip = in + (size_t)(yy*64 + xx)*256;
      const float* wp = w + (size_t)((dy*3 + dx)*256)*256 + co;
      for (int ci=0; ci<256; ci+=2) {
        s0 = fmaf(ip[ci],   wp[(size_t)ci*256],     s0);
        s1 = fmaf(ip[ci+1], wp[(size_t)(ci+1)*256], s1);
      }
    }
  }
  out[gid] = s0 + s1;
}

__global__ __launch_bounds__(256) void nchw_kernel(const float* __restrict__ in,
                                                   float* __restrict__ out) {
  int gid = blockIdx.x*256 + threadIdx.x;
  if (gid >= 256*64*64) return;
  int w = gid & 63; int h = (gid >> 6) & 63; int c = gid >> 12;
  out[gid] = in[(size_t)(h*64 + w)*256 + c];
}

// ================================================================ launch
extern "C" void kernel_launch(void* const* d_in, const int* in_sizes, int n_in,
                              void* d_out, int out_size, void* d_ws, size_t ws_size,
                              hipStream_t stream)
{
  const float* x_in   = (const float*)d_in[0];
  const float* ln1_g  = (const float*)d_in[1];
  const float* ln1_b  = (const float*)d_in[2];
  const float* qkv_w  = (const float*)d_in[3];
  const float* qkv_b  = (const float*)d_in[4];
  const float* proj_w = (const float*)d_in[5];
  const float* proj_b = (const float*)d_in[6];
  const float* rel_h  = (const float*)d_in[7];
  const float* rel_w  = (const float*)d_in[8];
  const float* ln2_g  = (const float*)d_in[9];
  const float* ln2_b  = (const float*)d_in[10];
  const float* fc1_w  = (const float*)d_in[11];
  const float* fc1_b  = (const float*)d_in[12];
  const float* fc2_w  = (const float*)d_in[13];
  const float* fc2_b  = (const float*)d_in[14];
  const float* nconv1 = (const float*)d_in[15];
  const float* nln1_g = (const float*)d_in[16];
  const float* nln1_b = (const float*)d_in[17];
  const float* nconv2 = (const float*)d_in[18];
  const float* nln2_g = (const float*)d_in[19];
  const float* nln2_b = (const float*)d_in[20];

  // workspace layout (floats)
  float*  ws     = (float*)d_ws;
  float*  xbuf   = ws;                                   // 3,145,728 fl
  ushort* bufCs  = (ushort*)(xbuf + 3145728);            // 3,763,200 sh (1,881,600 fl)
  float*  bufD   = xbuf + 3145728 + 1881600;             // 3,763,200 fl
  float*  bufQE  = bufD + 3763200;                       // 11,289,600 fl
  ushort* bufQEs = (ushort*)bufQE;
  ushort* rhB    = (ushort*)(bufQE + 11289600);          // 3,145,728 sh
  ushort* rwB    = rhB + 3145728;                        // 3,145,728 sh
  ushort* wqT    = rwB + 3145728;                        // 1,769,472 sh
  ushort* wpT    = wqT + 1769472;                        //   589,824 sh
  ushort* wf1T   = wpT + 589824;                         // 2,359,296 sh
  ushort* wf2T   = wf1T + 2359296;                       // 2,359,296 sh
  ushort* wnT    = wf2T + 2359296;                       //   196,608 sh
  ushort* bufDs  = (ushort*)bufD;

  copy_kernel<<<CDIV(3145728,256),256,0,stream>>>(xbuf, x_in, 3145728);

  for (int i = 0; i < 4; ++i) {
    int wsz = (i < 3) ? 14 : 0;
    transpose_cvt_kernel<<<dim3(2304/32, 768/32),256,0,stream>>>(qkv_w + (size_t)i*768*2304, wqT, 768, 2304);
    transpose_cvt_kernel<<<dim3(768/32,  768/32),256,0,stream>>>(proj_w + (size_t)i*768*768,  wpT, 768, 768);
    transpose_cvt_kernel<<<dim3(3072/32, 768/32),256,0,stream>>>(fc1_w + (size_t)i*768*3072, wf1T, 768, 3072);
    transpose_cvt_kernel<<<dim3(768/32, 3072/32),256,0,stream>>>(fc2_w + (size_t)i*3072*768, wf2T, 3072, 768);

    ln_kernel<<<4096,256,0,stream>>>(xbuf, ln1_g + i*768, ln1_b + i*768, nullptr, bufCs, 768, 1e-5f);
    int M, nWin, T, S;
    const ushort* qkvIn;
    if (wsz > 0) {
      winpart_kernel<<<CDIV(25*196*768,256),256,0,stream>>>(bufCs, bufDs);
      qkvIn = bufDs; M = 4900; nWin = 25; T = 196; S = 14;
    } else {
      qkvIn = bufCs; M = 4096; nWin = 1; T = 4096; S = 64;
    }
    gemm_bf16_kernel<<<dim3(2304/128, CDIV(M,128)),256,0,stream>>>(
        qkvIn, wqT, qkv_b + i*2304, nullptr, nullptr, bufQEs, M, 2304, 768, 0);
    int relTot = nWin*12*T*S;
    relbias_kernel<<<CDIV(relTot,256),256,0,stream>>>(bufQEs, rel_h + i*127*64, rhB, nWin, T, S, 1);
    relbias_kernel<<<CDIV(relTot,256),256,0,stream>>>(bufQEs, rel_w + i*127*64, rwB, nWin, T, S, 0);
    if (wsz > 0)
      attn3_kernel<14><<<dim3(4,12,25),256,0,stream>>>(bufQEs, rhB, rwB, bufCs, 196);
    else
      attn3_kernel<64><<<dim3(64,12,1),256,0,stream>>>(bufQEs, rhB, rwB, bufCs, 4096);
    gemm_bf16_kernel<<<dim3(768/128, CDIV(M,128)),256,0,stream>>>(
        bufCs, wpT, proj_b + i*768, nullptr, bufD, nullptr, M, 768, 768, 0);
    if (wsz > 0)
      unpart_add_kernel<<<CDIV(3145728,256),256,0,stream>>>(xbuf, bufD);
    else
      add_kernel<<<CDIV(3145728,256),256,0,stream>>>(xbuf, bufD, 3145728);
    // MLP
    ln_kernel<<<4096,256,0,stream>>>(xbuf, ln2_g + i*768, ln2_b + i*768, nullptr, bufCs, 768, 1e-5f);
    gemm_bf16_kernel<<<dim3(3072/128, 4096/128),256,0,stream>>>(
        bufCs, wf1T, fc1_b + i*3072, nullptr, nullptr, bufQEs, 4096, 3072, 768, 1);
    gemm_bf16_kernel<<<dim3(768/128, 4096/128),256,0,stream>>>(
        bufQEs, wf2T, fc2_b + i*768, xbuf, xbuf, nullptr, 4096, 768, 3072, 0);
  }

  // neck
  transpose_cvt_kernel<<<dim3(256/32, 768/32),256,0,stream>>>(nconv1, wnT, 768, 256);
  cvt_kernel<<<CDIV(3145728,256),256,0,stream>>>(xbuf, bufCs, 3145728);
  gemm_bf16_kernel<<<dim3(256/128, 4096/128),256,0,stream>>>(
      bufCs, wnT, nullptr, nullptr, bufD, nullptr, 4096, 256, 768, 0);
  ln_kernel<<<4096,256,0,stream>>>(bufD, nln1_g, nln1_b, bufQE, nullptr, 256, 1e-6f);
  conv3_kernel<<<CDIV(64*64*256,256),256,0,stream>>>(bufQE, nconv2, bufD);
  ln_kernel<<<4096,256,0,stream>>>(bufD, nln2_g, nln2_b, bufQE, nullptr, 256, 1e-6f);
  nchw_kernel<<<CDIV(1048576,256),256,0,stream>>>(bufQE, (float*)d_out);
}

// Round 4
// 2114.066 us; speedup vs baseline: 7.1771x; 1.2050x over previous
//
#include <hip/hip_runtime.h>
#include <math.h>

#define CDIV(a,b) (((a)+(b)-1)/(b))

typedef __attribute__((ext_vector_type(8))) short short8v;   // 8 bf16 = 4 VGPRs
typedef __attribute__((ext_vector_type(4))) float float4v;

__device__ __forceinline__ ushort f2b(float f) {
  union { float f; unsigned u; } v; v.f = f;
  unsigned r = (v.u + 0x7fffu + ((v.u >> 16) & 1u)) >> 16;   // RNE
  return (ushort)r;
}
__device__ __forceinline__ float b2f(ushort h) {
  union { unsigned u; float f; } v; v.u = ((unsigned)h) << 16;
  return v.f;
}

// ---------------------------------------------------------------- elementwise (vectorized)
__global__ __launch_bounds__(256) void copy4_kernel(float4* __restrict__ dst,
                                                    const float4* __restrict__ src, int n4) {
  int i = blockIdx.x*256 + threadIdx.x;
  if (i < n4) dst[i] = src[i];
}

__global__ __launch_bounds__(256) void cvt4_kernel(const float4* __restrict__ in,
                                                   ushort* __restrict__ out, int n4) {
  int i = blockIdx.x*256 + threadIdx.x;
  if (i >= n4) return;
  float4 v = in[i];
  ushort4 o; o.x = f2b(v.x); o.y = f2b(v.y); o.z = f2b(v.z); o.w = f2b(v.w);
  *(ushort4*)(out + (size_t)i*4) = o;
}

__global__ __launch_bounds__(256) void add4_kernel(float4* __restrict__ x,
                                                   const float4* __restrict__ y, int n4) {
  int i = blockIdx.x*256 + threadIdx.x;
  if (i >= n4) return;
  float4 a = x[i], b = y[i];
  a.x += b.x; a.y += b.y; a.z += b.z; a.w += b.w;
  x[i] = a;
}

// ---------------------------------------------------------------- LayerNorm, one wave per row
__global__ __launch_bounds__(256) void ln_kernel(const float* __restrict__ in,
    const float* __restrict__ g, const float* __restrict__ b,
    float* __restrict__ outf, ushort* __restrict__ outb, int C, float eps, int nrows)
{
  int row = blockIdx.x*4 + (threadIdx.x >> 6);
  int lane = threadIdx.x & 63;
  if (row >= nrows) return;
  const float* rp = in + (size_t)row*C;
  float s = 0.f, s2 = 0.f;
  for (int c = lane; c < C; c += 64) { float v = rp[c]; s += v; s2 += v*v; }
  #pragma unroll
  for (int off = 32; off > 0; off >>= 1) { s += __shfl_xor(s, off); s2 += __shfl_xor(s2, off); }
  float mean = s / C;
  float var  = s2 / C - mean*mean;
  float inv  = rsqrtf(var + eps);
  for (int c = lane; c < C; c += 64) {
    float v = (rp[c]-mean)*inv*g[c] + b[c];
    if (outb) outb[(size_t)row*C + c] = f2b(v);
    else      outf[(size_t)row*C + c] = v;
  }
}

// ---------------------------------------------------------------- window partition (bf16, 8-wide)
__global__ __launch_bounds__(256) void winpart_kernel(const ushort* __restrict__ in,
                                                      ushort* __restrict__ out) {
  int i = blockIdx.x*256 + threadIdx.x;          // over 25*196*96 uint4 units
  if (i >= 25*196*96) return;
  int c8 = i % 96; int t = (i / 96) % 196; int b = i / (96*196);
  int wy = b / 5, wx = b % 5;
  int iy = t / 14, ix = t % 14;
  int h = wy*14 + iy, w = wx*14 + ix;
  uint4 v = {0u,0u,0u,0u};
  if (h < 64 && w < 64) v = *(const uint4*)(in + ((size_t)(h*64 + w))*768 + c8*8);
  *(uint4*)(out + (size_t)i*8) = v;
}

// window unpartition + residual add (float4)
__global__ __launch_bounds__(256) void unpart_add_kernel(float* __restrict__ x,
                                                         const float* __restrict__ p) {
  int i = blockIdx.x*256 + threadIdx.x;          // over 4096*192 float4 units
  if (i >= 4096*192) return;
  int c4 = i % 192; int hw = i / 192; int w = hw % 64; int h = hw / 64;
  int wy = h/14, iy = h%14, wx = w/14, ix = w%14;
  int b = wy*5 + wx; int t = iy*14 + ix;
  float4 a = *(const float4*)(x + (size_t)i*4);
  float4 r = *(const float4*)(p + ((size_t)(b*196 + t))*768 + c4*4);
  a.x += r.x; a.y += r.y; a.z += r.z; a.w += r.w;
  *(float4*)(x + (size_t)i*4) = a;
}

// ---------------------------------------------------------------- weight transpose+convert: in [K][N] f32 -> out [N][K] bf16
__global__ __launch_bounds__(256) void transpose_cvt_kernel(const float* __restrict__ in,
    ushort* __restrict__ out, int K, int N)
{
  __shared__ float t[32][33];
  int n0 = blockIdx.x*32, k0 = blockIdx.y*32;
  int cc = threadIdx.x & 31, rr = threadIdx.x >> 5;
  for (int r = rr; r < 32; r += 8) t[r][cc] = in[(size_t)(k0+r)*N + n0 + cc];
  __syncthreads();
  for (int r = rr; r < 32; r += 8) out[(size_t)(n0+r)*K + k0 + cc] = f2b(t[cc][r]);
}

// f32 transpose: in [R][Cc] -> out [Cc][R]  (for NHWC->NCHW)
__global__ __launch_bounds__(256) void transpose_f32_kernel(const float* __restrict__ in,
    float* __restrict__ out, int R, int Cc)
{
  __shared__ float t[32][33];
  int c0 = blockIdx.x*32, r0 = blockIdx.y*32;
  int cc = threadIdx.x & 31, rr = threadIdx.x >> 5;
  for (int r = rr; r < 32; r += 8) t[r][cc] = in[(size_t)(r0+r)*Cc + c0 + cc];
  __syncthreads();
  for (int r = rr; r < 32; r += 8) out[(size_t)(c0+r)*R + r0 + cc] = t[cc][r];
}

// ---------------------------------------------------------------- bf16 MFMA GEMM
// A [M][K] bf16, Bt [N][K] bf16 (weights transposed). Out: Cf fp32 or Cb bf16.
__global__ __launch_bounds__(256) void gemm_bf16_kernel(
    const ushort* __restrict__ A, const ushort* __restrict__ Bt,
    const float* __restrict__ bias, const float* __restrict__ res,
    float* __restrict__ Cf, ushort* __restrict__ Cb,
    int M, int N, int K, int act)
{
  __shared__ ushort Al[128*40];
  __shared__ ushort Bl[128*40];
  int tid = threadIdx.x;
  int lane = tid & 63, wave = tid >> 6;
  int wm = wave & 1, wn = wave >> 1;
  int l15 = lane & 15, lq = lane >> 4;
  int rowBase = blockIdx.y * 128, colBase = blockIdx.x * 128;
  float4v acc[4][4];
  #pragma unroll
  for (int i=0;i<4;++i)
    #pragma unroll
    for (int j=0;j<4;++j) acc[i][j] = (float4v){0.f,0.f,0.f,0.f};

  int sRow = tid >> 1;
  int sCol = (tid & 1) << 4;
  int aRow = rowBase + sRow;
  bool aval = aRow < M;
  const ushort* aP = A  + (size_t)(aval ? aRow : 0) * K + sCol;
  const ushort* bP = Bt + (size_t)(colBase + sRow) * K + sCol;
  ushort* aL = Al + sRow*40 + sCol;
  ushort* bL = Bl + sRow*40 + sCol;
  uint4 z4 = {0u,0u,0u,0u};

  for (int k0 = 0; k0 < K; k0 += 32) {
    uint4 a0 = aval ? *(const uint4*)(aP + k0)     : z4;
    uint4 a1 = aval ? *(const uint4*)(aP + k0 + 8) : z4;
    uint4 b0 = *(const uint4*)(bP + k0);
    uint4 b1 = *(const uint4*)(bP + k0 + 8);
    __syncthreads();
    *(uint4*)aL = a0; *(uint4*)(aL + 8) = a1;
    *(uint4*)bL = b0; *(uint4*)(bL + 8) = b1;
    __syncthreads();
    short8v af[4], bf[4];
    #pragma unroll
    for (int mi=0; mi<4; ++mi)
      af[mi] = *(const short8v*)(Al + (wm*64 + mi*16 + l15)*40 + lq*8);
    #pragma unroll
    for (int ni=0; ni<4; ++ni)
      bf[ni] = *(const short8v*)(Bl + (wn*64 + ni*16 + l15)*40 + lq*8);
    #pragma unroll
    for (int mi=0; mi<4; ++mi)
      #pragma unroll
      for (int ni=0; ni<4; ++ni)
        acc[mi][ni] = __builtin_amdgcn_mfma_f32_16x16x32_bf16(af[mi], bf[ni], acc[mi][ni], 0, 0, 0);
  }
  #pragma unroll
  for (int mi=0; mi<4; ++mi) {
    int gr0 = rowBase + wm*64 + mi*16 + lq*4;
    #pragma unroll
    for (int ni=0; ni<4; ++ni) {
      int gc = colBase + wn*64 + ni*16 + l15;
      float bsv = bias ? bias[gc] : 0.f;
      #pragma unroll
      for (int r=0; r<4; ++r) {
        int gr = gr0 + r;
        if (gr < M) {
          float v = acc[mi][ni][r] + bsv;
          if (act) v = 0.5f*v*(1.f + erff(v*0.70710678118f));
          if (res) v += res[(size_t)gr*N + gc];
          if (Cf) Cf[(size_t)gr*N + gc] = v;
          else    Cb[(size_t)gr*N + gc] = f2b(v);
        }
      }
    }
  }
}

// ---------------------------------------------------------------- im2col for 3x3 SAME conv, bf16, 64x64x256
// out[p][tap*256+ci] = in[(y+dy-1)*64 + (x+dx-1)][ci]  (zero outside)
__global__ __launch_bounds__(256) void im2col3_kernel(const ushort* __restrict__ in,
                                                      ushort* __restrict__ out)
{
  int gid = blockIdx.x*256 + threadIdx.x;      // over 4096*288 uint4 units
  if (gid >= 4096*288) return;
  int u = gid % 288;  int p = gid / 288;
  int x = p & 63, y = p >> 6;
  int tap = u >> 5;                            // 0..8
  int cu  = u & 31;                            // chunk of 8 within 256
  int dy = tap / 3, dx = tap - dy*3;
  int yy = y + dy - 1, xx = x + dx - 1;
  uint4 v = {0u,0u,0u,0u};
  if (yy >= 0 && yy < 64 && xx >= 0 && xx < 64)
    v = *(const uint4*)(in + ((size_t)(yy*64 + xx))*256 + cu*8);
  *(uint4*)(out + (size_t)p*2304 + u*8) = v;
}

// ---------------------------------------------------------------- decomposed rel-pos bias (bf16 qkv in, bf16 out)
__global__ __launch_bounds__(256) void relbias_kernel(const ushort* __restrict__ qkv,
    const float* __restrict__ table, ushort* __restrict__ out,
    int nWin, int T, int S, int useH)
{
  int gid = blockIdx.x*256 + threadIdx.x;
  int total = nWin*12*T*S;
  if (gid >= total) return;
  int kk = gid % S; int r = gid / S;
  int t = r % T; int r2 = r / T; int n = r2 % 12; int b = r2 / 12;
  int coord = useH ? (t / S) : (t % S);
  const ushort* q = qkv + ((size_t)(b*T + t))*2304 + n*64;
  const float* tb = table + (size_t)(coord - kk + S - 1)*64;
  float s0=0.f, s1=0.f;
  #pragma unroll
  for (int d=0; d<64; d+=2) { s0 = fmaf(b2f(q[d]), tb[d], s0); s1 = fmaf(b2f(q[d+1]), tb[d+1], s1); }
  out[gid] = f2b(s0 + s1);
}

// ---------------------------------------------------------------- MFMA flash attention
template<int S>
__global__ __launch_bounds__(256) void attn3_kernel(
    const ushort* __restrict__ qkv, const ushort* __restrict__ rh,
    const ushort* __restrict__ rw, ushort* __restrict__ outb, int T)
{
  constexpr int SP = (S + 15) & ~15;
  __shared__ ushort Ql[64*72];
  __shared__ ushort Kl[64*72];
  __shared__ ushort Vt[64*72];
  __shared__ ushort Pl[64*72];
  __shared__ ushort RHl[64*SP];
  __shared__ ushort RWl[64*SP];

  int qt = blockIdx.x, n = blockIdx.y, b = blockIdx.z;
  int tid = threadIdx.x, lane = tid & 63, w = tid >> 6;
  int l15 = lane & 15, lq = lane >> 4;
  size_t tokBase = (size_t)b * T;
  int q0 = qt * 64;

  #pragma unroll
  for (int it = 0; it < 2; ++it) {
    int id = tid + it*256;
    int r = id >> 3, ch = id & 7;
    int qq = q0 + r; if (qq >= T) qq = T - 1;
    *(uint4*)(Ql + r*72 + ch*8) =
        *(const uint4*)(qkv + (tokBase + qq)*2304 + n*64 + ch*8);
  }
  for (int idx = tid; idx < 64*S; idx += 256) {
    int r = idx / S, c = idx - r*S;
    int qq = q0 + r; if (qq >= T) qq = T - 1;
    size_t base = ((size_t)(b*12 + n)*T + qq)*S;
    RHl[r*SP + c] = rh[base + c];
    RWl[r*SP + c] = rw[base + c];
  }

  float m[4], l[4];
  #pragma unroll
  for (int r=0;r<4;++r){ m[r]=-1e30f; l[r]=0.f; }
  float4v O[4];
  #pragma unroll
  for (int i=0;i<4;++i) O[i] = (float4v){0.f,0.f,0.f,0.f};

  int nkt = (T + 63) >> 6;
  for (int kt = 0; kt < nkt; ++kt) {
    int k0 = kt*64;
    __syncthreads();
    #pragma unroll
    for (int it=0; it<2; ++it) {
      int id = tid + it*256;
      int r = id >> 3, ch = id & 7;
      int kk = k0 + r; if (kk >= T) kk = T-1;
      *(uint4*)(Kl + r*72 + ch*8) =
        *(const uint4*)(qkv + (tokBase + kk)*2304 + 768 + n*64 + ch*8);
    }
    #pragma unroll
    for (int it=0; it<2; ++it) {
      int id = tid + it*256;
      int key = id & 63, dch = id >> 6;
      int kk = k0 + key; if (kk >= T) kk = T-1;
      union { uint4 v; ushort u[8]; } tv;
      tv.v = *(const uint4*)(qkv + (tokBase + kk)*2304 + 1536 + n*64 + dch*8);
      #pragma unroll
      for (int u=0;u<8;++u) Vt[(dch*8+u)*72 + key] = tv.u[u];
    }
    __syncthreads();

    short8v aq0 = *(const short8v*)(Ql + (w*16 + l15)*72 + lq*8);
    short8v aq1 = *(const short8v*)(Ql + (w*16 + l15)*72 + 32 + lq*8);
    float4v Sv[4];
    #pragma unroll
    for (int ni=0; ni<4; ++ni) {
      short8v bk0 = *(const short8v*)(Kl + (ni*16 + l15)*72 + lq*8);
      short8v bk1 = *(const short8v*)(Kl + (ni*16 + l15)*72 + 32 + lq*8);
      float4v s = (float4v){0.f,0.f,0.f,0.f};
      s = __builtin_amdgcn_mfma_f32_16x16x32_bf16(aq0, bk0, s, 0,0,0);
      s = __builtin_amdgcn_mfma_f32_16x16x32_bf16(aq1, bk1, s, 0,0,0);
      Sv[ni] = s;
    }

    float p[4][4];
    float alpha[4];
    #pragma unroll
    for (int r=0;r<4;++r) {
      int qlrow = w*16 + lq*4 + r;
      float sc[4];
      #pragma unroll
      for (int ni=0;ni<4;++ni) {
        int key = k0 + ni*16 + l15;
        int kcl = key < T ? key : 0;
        int kh = kcl / S, kw = kcl - kh*S;
        float v = Sv[ni][r]*0.125f + b2f(RHl[qlrow*SP+kh]) + b2f(RWl[qlrow*SP+kw]);
        sc[ni] = key < T ? v : -1e30f;
      }
      float mx = fmaxf(fmaxf(sc[0],sc[1]), fmaxf(sc[2],sc[3]));
      #pragma unroll
      for (int off=8; off>0; off>>=1) mx = fmaxf(mx, __shfl_xor(mx, off));
      float mn = fmaxf(m[r], mx);
      float al = __expf(m[r] - mn);
      m[r] = mn; alpha[r] = al;
      float rsum = 0.f;
      #pragma unroll
      for (int ni=0;ni<4;++ni) { float pv = __expf(sc[ni]-mn); p[ni][r] = pv; rsum += pv; }
      #pragma unroll
      for (int off=8; off>0; off>>=1) rsum += __shfl_xor(rsum, off);
      l[r] = l[r]*al + rsum;
    }
    #pragma unroll
    for (int ni=0;ni<4;++ni)
      #pragma unroll
      for (int r=0;r<4;++r)
        Pl[(w*16 + lq*4 + r)*72 + ni*16 + l15] = f2b(p[ni][r]);
    #pragma unroll
    for (int ni=0;ni<4;++ni)
      #pragma unroll
      for (int r=0;r<4;++r) O[ni][r] *= alpha[r];
    __syncthreads();

    short8v ap0 = *(const short8v*)(Pl + (w*16 + l15)*72 + lq*8);
    short8v ap1 = *(const short8v*)(Pl + (w*16 + l15)*72 + 32 + lq*8);
    #pragma unroll
    for (int ni=0;ni<4;++ni) {
      short8v bv0 = *(const short8v*)(Vt + (ni*16 + l15)*72 + lq*8);
      short8v bv1 = *(const short8v*)(Vt + (ni*16 + l15)*72 + 32 + lq*8);
      O[ni] = __builtin_amdgcn_mfma_f32_16x16x32_bf16(ap0, bv0, O[ni], 0,0,0);
      O[ni] = __builtin_amdgcn_mfma_f32_16x16x32_bf16(ap1, bv1, O[ni], 0,0,0);
    }
  }

  #pragma unroll
  for (int r=0;r<4;++r) {
    int qlrow = w*16 + lq*4 + r;
    int qg = q0 + qlrow;
    if (qg < T) {
      float inv = 1.f / l[r];
      #pragma unroll
      for (int ni=0;ni<4;++ni)
        outb[(tokBase + qg)*768 + n*64 + ni*16 + l15] = f2b(O[ni][r]*inv);
    }
  }
}

// ================================================================ launch
extern "C" void kernel_launch(void* const* d_in, const int* in_sizes, int n_in,
                              void* d_out, int out_size, void* d_ws, size_t ws_size,
                              hipStream_t stream)
{
  const float* x_in   = (const float*)d_in[0];
  const float* ln1_g  = (const float*)d_in[1];
  const float* ln1_b  = (const float*)d_in[2];
  const float* qkv_w  = (const float*)d_in[3];
  const float* qkv_b  = (const float*)d_in[4];
  const float* proj_w = (const float*)d_in[5];
  const float* proj_b = (const float*)d_in[6];
  const float* rel_h  = (const float*)d_in[7];
  const float* rel_w  = (const float*)d_in[8];
  const float* ln2_g  = (const float*)d_in[9];
  const float* ln2_b  = (const float*)d_in[10];
  const float* fc1_w  = (const float*)d_in[11];
  const float* fc1_b  = (const float*)d_in[12];
  const float* fc2_w  = (const float*)d_in[13];
  const float* fc2_b  = (const float*)d_in[14];
  const float* nconv1 = (const float*)d_in[15];
  const float* nln1_g = (const float*)d_in[16];
  const float* nln1_b = (const float*)d_in[17];
  const float* nconv2 = (const float*)d_in[18];
  const float* nln2_g = (const float*)d_in[19];
  const float* nln2_b = (const float*)d_in[20];

  // workspace layout (floats); total ~108.9 MB (118 MB proven available)
  float*  ws     = (float*)d_ws;
  float*  xbuf   = ws;                                   // 3,145,728 fl
  ushort* bufCs  = (ushort*)(xbuf + 3145728);            // 3,763,200 sh
  float*  bufD   = xbuf + 3145728 + 1881600;             // 3,763,200 fl
  float*  bufQE  = bufD + 3763200;                       // 11,289,600 fl
  ushort* bufQEs = (ushort*)bufQE;
  ushort* rhB    = (ushort*)(bufQE + 11289600);          // 3,145,728 sh
  ushort* rwB    = rhB + 3145728;                        // 3,145,728 sh
  ushort* wqT    = rwB + 3145728;                        // 1,769,472 sh
  ushort* wpT    = wqT + 1769472;                        //   589,824 sh
  ushort* wf1T   = wpT + 589824;                         // 2,359,296 sh
  ushort* wf2T   = wf1T + 2359296;                       // 2,359,296 sh
  ushort* wnT    = wf2T + 2359296;                       //   196,608 sh
  ushort* wn2T   = wnT + 196608;                         //   589,824 sh
  ushort* bufDs  = (ushort*)bufD;

  copy4_kernel<<<CDIV(786432,256),256,0,stream>>>((float4*)xbuf, (const float4*)x_in, 786432);

  for (int i = 0; i < 4; ++i) {
    int wsz = (i < 3) ? 14 : 0;
    transpose_cvt_kernel<<<dim3(2304/32, 768/32),256,0,stream>>>(qkv_w + (size_t)i*768*2304, wqT, 768, 2304);
    transpose_cvt_kernel<<<dim3(768/32,  768/32),256,0,stream>>>(proj_w + (size_t)i*768*768,  wpT, 768, 768);
    transpose_cvt_kernel<<<dim3(3072/32, 768/32),256,0,stream>>>(fc1_w + (size_t)i*768*3072, wf1T, 768, 3072);
    transpose_cvt_kernel<<<dim3(768/32, 3072/32),256,0,stream>>>(fc2_w + (size_t)i*3072*768, wf2T, 3072, 768);

    ln_kernel<<<1024,256,0,stream>>>(xbuf, ln1_g + i*768, ln1_b + i*768, nullptr, bufCs, 768, 1e-5f, 4096);
    int M;
    const ushort* qkvIn;
    int nWin, T, S;
    if (wsz > 0) {
      winpart_kernel<<<CDIV(25*196*96,256),256,0,stream>>>(bufCs, bufDs);
      qkvIn = bufDs; M = 4900; nWin = 25; T = 196; S = 14;
    } else {
      qkvIn = bufCs; M = 4096; nWin = 1; T = 4096; S = 64;
    }
    gemm_bf16_kernel<<<dim3(2304/128, CDIV(M,128)),256,0,stream>>>(
        qkvIn, wqT, qkv_b + i*2304, nullptr, nullptr, bufQEs, M, 2304, 768, 0);
    int relTot = nWin*12*T*S;
    relbias_kernel<<<CDIV(relTot,256),256,0,stream>>>(bufQEs, rel_h + i*127*64, rhB, nWin, T, S, 1);
    relbias_kernel<<<CDIV(relTot,256),256,0,stream>>>(bufQEs, rel_w + i*127*64, rwB, nWin, T, S, 0);
    if (wsz > 0)
      attn3_kernel<14><<<dim3(4,12,25),256,0,stream>>>(bufQEs, rhB, rwB, bufCs, 196);
    else
      attn3_kernel<64><<<dim3(64,12,1),256,0,stream>>>(bufQEs, rhB, rwB, bufCs, 4096);
    gemm_bf16_kernel<<<dim3(768/128, CDIV(M,128)),256,0,stream>>>(
        bufCs, wpT, proj_b + i*768, nullptr, bufD, nullptr, M, 768, 768, 0);
    if (wsz > 0)
      unpart_add_kernel<<<CDIV(4096*192,256),256,0,stream>>>(xbuf, bufD);
    else
      add4_kernel<<<CDIV(786432,256),256,0,stream>>>((float4*)xbuf, (const float4*)bufD, 786432);
    // MLP
    ln_kernel<<<1024,256,0,stream>>>(xbuf, ln2_g + i*768, ln2_b + i*768, nullptr, bufCs, 768, 1e-5f, 4096);
    gemm_bf16_kernel<<<dim3(3072/128, 4096/128),256,0,stream>>>(
        bufCs, wf1T, fc1_b + i*3072, nullptr, nullptr, bufQEs, 4096, 3072, 768, 1);
    gemm_bf16_kernel<<<dim3(768/128, 4096/128),256,0,stream>>>(
        bufQEs, wf2T, fc2_b + i*768, xbuf, xbuf, nullptr, 4096, 768, 3072, 0);
  }

  // neck
  transpose_cvt_kernel<<<dim3(256/32, 768/32),256,0,stream>>>(nconv1, wnT, 768, 256);
  transpose_cvt_kernel<<<dim3(256/32, 2304/32),256,0,stream>>>(nconv2, wn2T, 2304, 256);
  cvt4_kernel<<<CDIV(786432,256),256,0,stream>>>((const float4*)xbuf, bufCs, 786432);
  gemm_bf16_kernel<<<dim3(256/128, 4096/128),256,0,stream>>>(
      bufCs, wnT, nullptr, nullptr, bufD, nullptr, 4096, 256, 768, 0);
  // LN2d #1 -> bf16 for im2col
  ln_kernel<<<1024,256,0,stream>>>(bufD, nln1_g, nln1_b, nullptr, bufCs, 256, 1e-6f, 4096);
  // im2col + MFMA GEMM = 3x3 conv
  im2col3_kernel<<<CDIV(4096*288,256),256,0,stream>>>(bufCs, bufQEs);
  gemm_bf16_kernel<<<dim3(256/128, 4096/128),256,0,stream>>>(
      bufQEs, wn2T, nullptr, nullptr, bufD, nullptr, 4096, 256, 2304, 0);
  // LN2d #2 -> fp32, then NHWC->NCHW transpose
  ln_kernel<<<1024,256,0,stream>>>(bufD, nln2_g, nln2_b, bufQE, nullptr, 256, 1e-6f, 4096);
  transpose_f32_kernel<<<dim3(256/32, 4096/32),256,0,stream>>>(bufQE, (float*)d_out, 4096, 256);
}

// Round 5
// 2009.794 us; speedup vs baseline: 7.5494x; 1.0519x over previous
//
#include <hip/hip_runtime.h>
#include <math.h>

#define CDIV(a,b) (((a)+(b)-1)/(b))

typedef __attribute__((ext_vector_type(8))) short short8v;   // 8 bf16 = 4 VGPRs
typedef __attribute__((ext_vector_type(4))) float float4v;

__device__ __forceinline__ ushort f2b(float f) {
  union { float f; unsigned u; } v; v.f = f;
  unsigned r = (v.u + 0x7fffu + ((v.u >> 16) & 1u)) >> 16;   // RNE
  return (ushort)r;
}
__device__ __forceinline__ float b2f(ushort h) {
  union { unsigned u; float f; } v; v.u = ((unsigned)h) << 16;
  return v.f;
}

// async global->LDS, 16B per lane; lds base must be wave-uniform (HW adds lane*16)
__device__ __forceinline__ void gload_lds16(const ushort* g, ushort* l) {
  __builtin_amdgcn_global_load_lds(
      (const __attribute__((address_space(1))) void*)g,
      (__attribute__((address_space(3))) void*)l, 16, 0, 0);
}

// ---------------------------------------------------------------- elementwise (vectorized)
__global__ __launch_bounds__(256) void copy4_kernel(float4* __restrict__ dst,
                                                    const float4* __restrict__ src, int n4) {
  int i = blockIdx.x*256 + threadIdx.x;
  if (i < n4) dst[i] = src[i];
}

__global__ __launch_bounds__(256) void add4_kernel(float4* __restrict__ x,
                                                   const float4* __restrict__ y, int n4) {
  int i = blockIdx.x*256 + threadIdx.x;
  if (i >= n4) return;
  float4 a = x[i], b = y[i];
  a.x += b.x; a.y += b.y; a.z += b.z; a.w += b.w;
  x[i] = a;
}

// ---------------------------------------------------------------- LayerNorm, one wave per row
__global__ __launch_bounds__(256) void ln_kernel(const float* __restrict__ in,
    const float* __restrict__ g, const float* __restrict__ b,
    float* __restrict__ outf, ushort* __restrict__ outb, int C, float eps, int nrows)
{
  int row = blockIdx.x*4 + (threadIdx.x >> 6);
  int lane = threadIdx.x & 63;
  if (row >= nrows) return;
  const float* rp = in + (size_t)row*C;
  float s = 0.f, s2 = 0.f;
  for (int c = lane; c < C; c += 64) { float v = rp[c]; s += v; s2 += v*v; }
  #pragma unroll
  for (int off = 32; off > 0; off >>= 1) { s += __shfl_xor(s, off); s2 += __shfl_xor(s2, off); }
  float mean = s / C;
  float var  = s2 / C - mean*mean;
  float inv  = rsqrtf(var + eps);
  for (int c = lane; c < C; c += 64) {
    float v = (rp[c]-mean)*inv*g[c] + b[c];
    if (outb) outb[(size_t)row*C + c] = f2b(v);
    else      outf[(size_t)row*C + c] = v;
  }
}

// ---------------------------------------------------------------- window partition (bf16, 8-wide)
__global__ __launch_bounds__(256) void winpart_kernel(const ushort* __restrict__ in,
                                                      ushort* __restrict__ out) {
  int i = blockIdx.x*256 + threadIdx.x;          // over 25*196*96 uint4 units
  if (i >= 25*196*96) return;
  int c8 = i % 96; int t = (i / 96) % 196; int b = i / (96*196);
  int wy = b / 5, wx = b % 5;
  int iy = t / 14, ix = t % 14;
  int h = wy*14 + iy, w = wx*14 + ix;
  uint4 v = {0u,0u,0u,0u};
  if (h < 64 && w < 64) v = *(const uint4*)(in + ((size_t)(h*64 + w))*768 + c8*8);
  *(uint4*)(out + (size_t)i*8) = v;
}

// window unpartition + residual add (float4)
__global__ __launch_bounds__(256) void unpart_add_kernel(float* __restrict__ x,
                                                         const float* __restrict__ p) {
  int i = blockIdx.x*256 + threadIdx.x;          // over 4096*192 float4 units
  if (i >= 4096*192) return;
  int c4 = i % 192; int hw = i / 192; int w = hw % 64; int h = hw / 64;
  int wy = h/14, iy = h%14, wx = w/14, ix = w%14;
  int b = wy*5 + wx; int t = iy*14 + ix;
  float4 a = *(const float4*)(x + (size_t)i*4);
  float4 r = *(const float4*)(p + ((size_t)(b*196 + t))*768 + c4*4);
  a.x += r.x; a.y += r.y; a.z += r.z; a.w += r.w;
  *(float4*)(x + (size_t)i*4) = a;
}

// ---------------------------------------------------------------- weight transpose+convert: in [K][N] f32 -> out [N][K] bf16
__global__ __launch_bounds__(256) void transpose_cvt_kernel(const float* __restrict__ in,
    ushort* __restrict__ out, int K, int N)
{
  __shared__ float t[32][33];
  int n0 = blockIdx.x*32, k0 = blockIdx.y*32;
  int cc = threadIdx.x & 31, rr = threadIdx.x >> 5;
  for (int r = rr; r < 32; r += 8) t[r][cc] = in[(size_t)(k0+r)*N + n0 + cc];
  __syncthreads();
  for (int r = rr; r < 32; r += 8) out[(size_t)(n0+r)*K + k0 + cc] = f2b(t[cc][r]);
}

// f32 transpose: in [R][Cc] -> out [Cc][R]  (for NHWC->NCHW)
__global__ __launch_bounds__(256) void transpose_f32_kernel(const float* __restrict__ in,
    float* __restrict__ out, int R, int Cc)
{
  __shared__ float t[32][33];
  int c0 = blockIdx.x*32, r0 = blockIdx.y*32;
  int cc = threadIdx.x & 31, rr = threadIdx.x >> 5;
  for (int r = rr; r < 32; r += 8) t[r][cc] = in[(size_t)(r0+r)*Cc + c0 + cc];
  __syncthreads();
  for (int r = rr; r < 32; r += 8) out[(size_t)(c0+r)*R + r0 + cc] = t[cc][r];
}

// ---------------------------------------------------------------- bf16 MFMA GEMM (m97 structure)
// A [M][K] bf16, Bt [N][K] bf16. 128x128 tile, BK=32, global_load_lds staging.
// LDS layout [row][32k] unpadded; bank swizzle applied on the GLOBAL side:
// LDS[row][c] holds k-chunk c ^ ((row>>1)&3)  (16B chunks).
__global__ __launch_bounds__(256) void gemm_bf16_kernel(
    const ushort* __restrict__ A, const ushort* __restrict__ Bt,
    const float* __restrict__ bias, const float* __restrict__ res,
    float* __restrict__ Cf, ushort* __restrict__ Cb,
    int M, int N, int K, int act)
{
  __shared__ ushort Al[128*32];
  __shared__ ushort Bl[128*32];
  int tid = threadIdx.x;
  int lane = tid & 63, wave = tid >> 6;
  int wm = wave & 1, wn = wave >> 1;
  int l15 = lane & 15, lq = lane >> 4;
  int rowBase = blockIdx.y * 128, colBase = blockIdx.x * 128;
  float4v acc[4][4];
  #pragma unroll
  for (int i=0;i<4;++i)
    #pragma unroll
    for (int j=0;j<4;++j) acc[i][j] = (float4v){0.f,0.f,0.f,0.f};

  // staging addresses: wave handles rows wave*16..+15 (iter0) and +64 (iter1)
  int rA0 = wave*16 + (lane>>2);
  int rA1 = rA0 + 64;
  int cs  = (lane&3) ^ ((lane>>3)&3);           // swizzled source chunk
  int gr0 = rowBase + rA0; if (gr0 >= M) gr0 = M-1;
  int gr1 = rowBase + rA1; if (gr1 >= M) gr1 = M-1;
  const ushort* aG0 = A  + (size_t)gr0*K + cs*8;
  const ushort* aG1 = A  + (size_t)gr1*K + cs*8;
  const ushort* bG0 = Bt + (size_t)(colBase + rA0)*K + cs*8;
  const ushort* bG1 = Bt + (size_t)(colBase + rA1)*K + cs*8;
  ushort* aL0 = Al + (wave*16)*32;              // wave-uniform LDS bases
  ushort* aL1 = Al + (64 + wave*16)*32;
  ushort* bL0 = Bl + (wave*16)*32;
  ushort* bL1 = Bl + (64 + wave*16)*32;

  int sA = (l15 >> 1) & 3;                      // read-side swizzle
  int rdOff = ((lq ^ sA) << 3);

  for (int k0 = 0; k0 < K; k0 += 32) {
    __syncthreads();
    gload_lds16(aG0 + k0, aL0);
    gload_lds16(aG1 + k0, aL1);
    gload_lds16(bG0 + k0, bL0);
    gload_lds16(bG1 + k0, bL1);
    __syncthreads();
    short8v af[4], bf[4];
    #pragma unroll
    for (int mi=0; mi<4; ++mi)
      af[mi] = *(const short8v*)(Al + (wm*64 + mi*16 + l15)*32 + rdOff);
    #pragma unroll
    for (int ni=0; ni<4; ++ni)
      bf[ni] = *(const short8v*)(Bl + (wn*64 + ni*16 + l15)*32 + rdOff);
    #pragma unroll
    for (int mi=0; mi<4; ++mi)
      #pragma unroll
      for (int ni=0; ni<4; ++ni)
        acc[mi][ni] = __builtin_amdgcn_mfma_f32_16x16x32_bf16(af[mi], bf[ni], acc[mi][ni], 0, 0, 0);
  }
  #pragma unroll
  for (int mi=0; mi<4; ++mi) {
    int gr0e = rowBase + wm*64 + mi*16 + lq*4;
    #pragma unroll
    for (int ni=0; ni<4; ++ni) {
      int gc = colBase + wn*64 + ni*16 + l15;
      float bsv = bias ? bias[gc] : 0.f;
      #pragma unroll
      for (int r=0; r<4; ++r) {
        int gr = gr0e + r;
        if (gr < M) {
          float v = acc[mi][ni][r] + bsv;
          if (act) v = 0.5f*v*(1.f + erff(v*0.70710678118f));
          if (res) v += res[(size_t)gr*N + gc];
          if (Cf) Cf[(size_t)gr*N + gc] = v;
          if (Cb) Cb[(size_t)gr*N + gc] = f2b(v);
        }
      }
    }
  }
}

// ---------------------------------------------------------------- im2col for 3x3 SAME conv, bf16, 64x64x256
__global__ __launch_bounds__(256) void im2col3_kernel(const ushort* __restrict__ in,
                                                      ushort* __restrict__ out)
{
  int gid = blockIdx.x*256 + threadIdx.x;      // over 4096*288 uint4 units
  if (gid >= 4096*288) return;
  int u = gid % 288;  int p = gid / 288;
  int x = p & 63, y = p >> 6;
  int tap = u >> 5;
  int cu  = u & 31;
  int dy = tap / 3, dx = tap - dy*3;
  int yy = y + dy - 1, xx = x + dx - 1;
  uint4 v = {0u,0u,0u,0u};
  if (yy >= 0 && yy < 64 && xx >= 0 && xx < 64)
    v = *(const uint4*)(in + ((size_t)(yy*64 + xx))*256 + cu*8);
  *(uint4*)(out + (size_t)p*2304 + u*8) = v;
}

// ---------------------------------------------------------------- decomposed rel-pos bias (bf16 qkv in, bf16 out)
__global__ __launch_bounds__(256) void relbias_kernel(const ushort* __restrict__ qkv,
    const float* __restrict__ table, ushort* __restrict__ out,
    int nWin, int T, int S, int useH)
{
  int gid = blockIdx.x*256 + threadIdx.x;
  int total = nWin*12*T*S;
  if (gid >= total) return;
  int kk = gid % S; int r = gid / S;
  int t = r % T; int r2 = r / T; int n = r2 % 12; int b = r2 / 12;
  int coord = useH ? (t / S) : (t % S);
  const ushort* q = qkv + ((size_t)(b*T + t))*2304 + n*64;
  const float* tb = table + (size_t)(coord - kk + S - 1)*64;
  float s0=0.f, s1=0.f;
  #pragma unroll
  for (int d=0; d<64; d+=2) { s0 = fmaf(b2f(q[d]), tb[d], s0); s1 = fmaf(b2f(q[d+1]), tb[d+1], s1); }
  out[gid] = f2b(s0 + s1);
}

// ---------------------------------------------------------------- MFMA flash attention (windowed, generic)
template<int S>
__global__ __launch_bounds__(256) void attn3_kernel(
    const ushort* __restrict__ qkv, const ushort* __restrict__ rh,
    const ushort* __restrict__ rw, ushort* __restrict__ outb, int T)
{
  constexpr int SP = (S + 15) & ~15;
  __shared__ ushort Ql[64*72];
  __shared__ ushort Kl[64*72];
  __shared__ ushort Vt[64*72];
  __shared__ ushort Pl[64*72];
  __shared__ ushort RHl[64*SP];
  __shared__ ushort RWl[64*SP];

  int qt = blockIdx.x, n = blockIdx.y, b = blockIdx.z;
  int tid = threadIdx.x, lane = tid & 63, w = tid >> 6;
  int l15 = lane & 15, lq = lane >> 4;
  size_t tokBase = (size_t)b * T;
  int q0 = qt * 64;

  #pragma unroll
  for (int it = 0; it < 2; ++it) {
    int id = tid + it*256;
    int r = id >> 3, ch = id & 7;
    int qq = q0 + r; if (qq >= T) qq = T - 1;
    *(uint4*)(Ql + r*72 + ch*8) =
        *(const uint4*)(qkv + (tokBase + qq)*2304 + n*64 + ch*8);
  }
  for (int idx = tid; idx < 64*S; idx += 256) {
    int r = idx / S, c = idx - r*S;
    int qq = q0 + r; if (qq >= T) qq = T - 1;
    size_t base = ((size_t)(b*12 + n)*T + qq)*S;
    RHl[r*SP + c] = rh[base + c];
    RWl[r*SP + c] = rw[base + c];
  }

  float m[4], l[4];
  #pragma unroll
  for (int r=0;r<4;++r){ m[r]=-1e30f; l[r]=0.f; }
  float4v O[4];
  #pragma unroll
  for (int i=0;i<4;++i) O[i] = (float4v){0.f,0.f,0.f,0.f};

  int nkt = (T + 63) >> 6;
  for (int kt = 0; kt < nkt; ++kt) {
    int k0 = kt*64;
    __syncthreads();
    #pragma unroll
    for (int it=0; it<2; ++it) {
      int id = tid + it*256;
      int r = id >> 3, ch = id & 7;
      int kk = k0 + r; if (kk >= T) kk = T-1;
      *(uint4*)(Kl + r*72 + ch*8) =
        *(const uint4*)(qkv + (tokBase + kk)*2304 + 768 + n*64 + ch*8);
    }
    #pragma unroll
    for (int it=0; it<2; ++it) {
      int id = tid + it*256;
      int key = id & 63, dch = id >> 6;
      int kk = k0 + key; if (kk >= T) kk = T-1;
      union { uint4 v; ushort u[8]; } tv;
      tv.v = *(const uint4*)(qkv + (tokBase + kk)*2304 + 1536 + n*64 + dch*8);
      #pragma unroll
      for (int u=0;u<8;++u) Vt[(dch*8+u)*72 + key] = tv.u[u];
    }
    __syncthreads();

    short8v aq0 = *(const short8v*)(Ql + (w*16 + l15)*72 + lq*8);
    short8v aq1 = *(const short8v*)(Ql + (w*16 + l15)*72 + 32 + lq*8);
    float4v Sv[4];
    #pragma unroll
    for (int ni=0; ni<4; ++ni) {
      short8v bk0 = *(const short8v*)(Kl + (ni*16 + l15)*72 + lq*8);
      short8v bk1 = *(const short8v*)(Kl + (ni*16 + l15)*72 + 32 + lq*8);
      float4v s = (float4v){0.f,0.f,0.f,0.f};
      s = __builtin_amdgcn_mfma_f32_16x16x32_bf16(aq0, bk0, s, 0,0,0);
      s = __builtin_amdgcn_mfma_f32_16x16x32_bf16(aq1, bk1, s, 0,0,0);
      Sv[ni] = s;
    }

    float p[4][4];
    float alpha[4];
    #pragma unroll
    for (int r=0;r<4;++r) {
      int qlrow = w*16 + lq*4 + r;
      float sc[4];
      #pragma unroll
      for (int ni=0;ni<4;++ni) {
        int key = k0 + ni*16 + l15;
        int kcl = key < T ? key : 0;
        int kh = kcl / S, kw = kcl - kh*S;
        float v = Sv[ni][r]*0.125f + b2f(RHl[qlrow*SP+kh]) + b2f(RWl[qlrow*SP+kw]);
        sc[ni] = key < T ? v : -1e30f;
      }
      float mx = fmaxf(fmaxf(sc[0],sc[1]), fmaxf(sc[2],sc[3]));
      #pragma unroll
      for (int off=8; off>0; off>>=1) mx = fmaxf(mx, __shfl_xor(mx, off));
      float mn = fmaxf(m[r], mx);
      float al = __expf(m[r] - mn);
      m[r] = mn; alpha[r] = al;
      float rsum = 0.f;
      #pragma unroll
      for (int ni=0;ni<4;++ni) { float pv = __expf(sc[ni]-mn); p[ni][r] = pv; rsum += pv; }
      #pragma unroll
      for (int off=8; off>0; off>>=1) rsum += __shfl_xor(rsum, off);
      l[r] = l[r]*al + rsum;
    }
    #pragma unroll
    for (int ni=0;ni<4;++ni)
      #pragma unroll
      for (int r=0;r<4;++r)
        Pl[(w*16 + lq*4 + r)*72 + ni*16 + l15] = f2b(p[ni][r]);
    #pragma unroll
    for (int ni=0;ni<4;++ni)
      #pragma unroll
      for (int r=0;r<4;++r) O[ni][r] *= alpha[r];
    __syncthreads();

    short8v ap0 = *(const short8v*)(Pl + (w*16 + l15)*72 + lq*8);
    short8v ap1 = *(const short8v*)(Pl + (w*16 + l15)*72 + 32 + lq*8);
    #pragma unroll
    for (int ni=0;ni<4;++ni) {
      short8v bv0 = *(const short8v*)(Vt + (ni*16 + l15)*72 + lq*8);
      short8v bv1 = *(const short8v*)(Vt + (ni*16 + l15)*72 + 32 + lq*8);
      O[ni] = __builtin_amdgcn_mfma_f32_16x16x32_bf16(ap0, bv0, O[ni], 0,0,0);
      O[ni] = __builtin_amdgcn_mfma_f32_16x16x32_bf16(ap1, bv1, O[ni], 0,0,0);
    }
  }

  #pragma unroll
  for (int r=0;r<4;++r) {
    int qlrow = w*16 + lq*4 + r;
    int qg = q0 + qlrow;
    if (qg < T) {
      float inv = 1.f / l[r];
      #pragma unroll
      for (int ni=0;ni<4;++ni)
        outb[(tokBase + qg)*768 + n*64 + ni*16 + l15] = f2b(O[ni][r]*inv);
    }
  }
}

// ---------------------------------------------------------------- specialized global flash attention
// T=4096, S=64, tile=64 keys: kh = kt (uniform per tile), kw = col (fixed per lane).
// Bias folds to 1 fma per score. No masks (all tiles full).
__global__ __launch_bounds__(256) void attn4_kernel(
    const ushort* __restrict__ qkv, const ushort* __restrict__ rh,
    const ushort* __restrict__ rw, ushort* __restrict__ outb)
{
  const int T = 4096;
  __shared__ ushort Ql[64*72];
  __shared__ ushort Kl[64*72];
  __shared__ ushort Vt[64*72];
  __shared__ ushort Pl[64*72];
  __shared__ ushort RHl[64*64];   // [qrow][kh]

  int qt = blockIdx.x, n = blockIdx.y;
  int tid = threadIdx.x, lane = tid & 63, w = tid >> 6;
  int l15 = lane & 15, lq = lane >> 4;
  int q0 = qt * 64;

  #pragma unroll
  for (int it = 0; it < 2; ++it) {
    int id = tid + it*256;
    int r = id >> 3, ch = id & 7;
    *(uint4*)(Ql + r*72 + ch*8) =
        *(const uint4*)(qkv + (size_t)(q0 + r)*2304 + n*64 + ch*8);
    *(uint4*)(RHl + r*64 + ch*8) =
        *(const uint4*)(rh + ((size_t)n*T + q0 + r)*64 + ch*8);
  }
  // preload this lane's rw values (kw = ni*16+l15, fixed across tiles)
  float rwp[4][4];
  #pragma unroll
  for (int r=0;r<4;++r)
    #pragma unroll
    for (int ni=0;ni<4;++ni)
      rwp[r][ni] = b2f(rw[((size_t)n*T + q0 + w*16 + lq*4 + r)*64 + ni*16 + l15]);

  float m[4], l[4];
  #pragma unroll
  for (int r=0;r<4;++r){ m[r]=-1e30f; l[r]=0.f; }
  float4v O[4];
  #pragma unroll
  for (int i=0;i<4;++i) O[i] = (float4v){0.f,0.f,0.f,0.f};

  for (int kt = 0; kt < 64; ++kt) {
    int k0 = kt*64;
    __syncthreads();
    #pragma unroll
    for (int it=0; it<2; ++it) {
      int id = tid + it*256;
      int r = id >> 3, ch = id & 7;
      *(uint4*)(Kl + r*72 + ch*8) =
        *(const uint4*)(qkv + (size_t)(k0 + r)*2304 + 768 + n*64 + ch*8);
    }
    #pragma unroll
    for (int it=0; it<2; ++it) {
      int id = tid + it*256;
      int key = id & 63, dch = id >> 6;
      union { uint4 v; ushort u[8]; } tv;
      tv.v = *(const uint4*)(qkv + (size_t)(k0 + key)*2304 + 1536 + n*64 + dch*8);
      #pragma unroll
      for (int u=0;u<8;++u) Vt[(dch*8+u)*72 + key] = tv.u[u];
    }
    __syncthreads();

    short8v aq0 = *(const short8v*)(Ql + (w*16 + l15)*72 + lq*8);
    short8v aq1 = *(const short8v*)(Ql + (w*16 + l15)*72 + 32 + lq*8);
    float4v Sv[4];
    #pragma unroll
    for (int ni=0; ni<4; ++ni) {
      short8v bk0 = *(const short8v*)(Kl + (ni*16 + l15)*72 + lq*8);
      short8v bk1 = *(const short8v*)(Kl + (ni*16 + l15)*72 + 32 + lq*8);
      float4v s = (float4v){0.f,0.f,0.f,0.f};
      s = __builtin_amdgcn_mfma_f32_16x16x32_bf16(aq0, bk0, s, 0,0,0);
      s = __builtin_amdgcn_mfma_f32_16x16x32_bf16(aq1, bk1, s, 0,0,0);
      Sv[ni] = s;
    }

    float alpha[4];
    #pragma unroll
    for (int r=0;r<4;++r) {
      int qlrow = w*16 + lq*4 + r;
      float rhv = b2f(RHl[qlrow*64 + kt]);   // broadcast read
      float sc[4];
      #pragma unroll
      for (int ni=0;ni<4;++ni)
        sc[ni] = fmaf(Sv[ni][r], 0.125f, rhv + rwp[r][ni]);
      float mx = fmaxf(fmaxf(sc[0],sc[1]), fmaxf(sc[2],sc[3]));
      #pragma unroll
      for (int off=8; off>0; off>>=1) mx = fmaxf(mx, __shfl_xor(mx, off));
      float mn = fmaxf(m[r], mx);
      float al = __expf(m[r] - mn);
      m[r] = mn; alpha[r] = al;
      float rsum = 0.f;
      #pragma unroll
      for (int ni=0;ni<4;++ni) {
        float pv = __expf(sc[ni]-mn);
        rsum += pv;
        union { float f; unsigned u; } cv; cv.f = pv;
        Pl[qlrow*72 + ni*16 + l15] = (ushort)((cv.u + 0x8000u) >> 16);  // cheap round
      }
      #pragma unroll
      for (int off=8; off>0; off>>=1) rsum += __shfl_xor(rsum, off);
      l[r] = l[r]*al + rsum;
    }
    #pragma unroll
    for (int ni=0;ni<4;++ni)
      #pragma unroll
      for (int r=0;r<4;++r) O[ni][r] *= alpha[r];

    // P rows are intra-wave (write rows w*16+lq*4+r, read rows w*16+l15) -> no barrier
    short8v ap0 = *(const short8v*)(Pl + (w*16 + l15)*72 + lq*8);
    short8v ap1 = *(const short8v*)(Pl + (w*16 + l15)*72 + 32 + lq*8);
    #pragma unroll
    for (int ni=0;ni<4;++ni) {
      short8v bv0 = *(const short8v*)(Vt + (ni*16 + l15)*72 + lq*8);
      short8v bv1 = *(const short8v*)(Vt + (ni*16 + l15)*72 + 32 + lq*8);
      O[ni] = __builtin_amdgcn_mfma_f32_16x16x32_bf16(ap0, bv0, O[ni], 0,0,0);
      O[ni] = __builtin_amdgcn_mfma_f32_16x16x32_bf16(ap1, bv1, O[ni], 0,0,0);
    }
  }

  #pragma unroll
  for (int r=0;r<4;++r) {
    int qg = q0 + w*16 + lq*4 + r;
    float inv = 1.f / l[r];
    #pragma unroll
    for (int ni=0;ni<4;++ni)
      outb[(size_t)qg*768 + n*64 + ni*16 + l15] = f2b(O[ni][r]*inv);
  }
}

// ================================================================ launch
extern "C" void kernel_launch(void* const* d_in, const int* in_sizes, int n_in,
                              void* d_out, int out_size, void* d_ws, size_t ws_size,
                              hipStream_t stream)
{
  const float* x_in   = (const float*)d_in[0];
  const float* ln1_g  = (const float*)d_in[1];
  const float* ln1_b  = (const float*)d_in[2];
  const float* qkv_w  = (const float*)d_in[3];
  const float* qkv_b  = (const float*)d_in[4];
  const float* proj_w = (const float*)d_in[5];
  const float* proj_b = (const float*)d_in[6];
  const float* rel_h  = (const float*)d_in[7];
  const float* rel_w  = (const float*)d_in[8];
  const float* ln2_g  = (const float*)d_in[9];
  const float* ln2_b  = (const float*)d_in[10];
  const float* fc1_w  = (const float*)d_in[11];
  const float* fc1_b  = (const float*)d_in[12];
  const float* fc2_w  = (const float*)d_in[13];
  const float* fc2_b  = (const float*)d_in[14];
  const float* nconv1 = (const float*)d_in[15];
  const float* nln1_g = (const float*)d_in[16];
  const float* nln1_b = (const float*)d_in[17];
  const float* nconv2 = (const float*)d_in[18];
  const float* nln2_g = (const float*)d_in[19];
  const float* nln2_b = (const float*)d_in[20];

  // workspace layout (floats); total ~108.9 MB
  float*  ws     = (float*)d_ws;
  float*  xbuf   = ws;                                   // 3,145,728 fl
  ushort* bufCs  = (ushort*)(xbuf + 3145728);            // 3,763,200 sh
  float*  bufD   = xbuf + 3145728 + 1881600;             // 3,763,200 fl
  float*  bufQE  = bufD + 3763200;                       // 11,289,600 fl
  ushort* bufQEs = (ushort*)bufQE;
  ushort* rhB    = (ushort*)(bufQE + 11289600);          // 3,145,728 sh
  ushort* rwB    = rhB + 3145728;                        // 3,145,728 sh
  ushort* wqT    = rwB + 3145728;                        // 1,769,472 sh
  ushort* wpT    = wqT + 1769472;                        //   589,824 sh
  ushort* wf1T   = wpT + 589824;                         // 2,359,296 sh
  ushort* wf2T   = wf1T + 2359296;                       // 2,359,296 sh
  ushort* wnT    = wf2T + 2359296;                       //   196,608 sh
  ushort* wn2T   = wnT + 196608;                         //   589,824 sh
  ushort* bufDs  = (ushort*)bufD;

  copy4_kernel<<<CDIV(786432,256),256,0,stream>>>((float4*)xbuf, (const float4*)x_in, 786432);

  for (int i = 0; i < 4; ++i) {
    int wsz = (i < 3) ? 14 : 0;
    transpose_cvt_kernel<<<dim3(2304/32, 768/32),256,0,stream>>>(qkv_w + (size_t)i*768*2304, wqT, 768, 2304);
    transpose_cvt_kernel<<<dim3(768/32,  768/32),256,0,stream>>>(proj_w + (size_t)i*768*768,  wpT, 768, 768);
    transpose_cvt_kernel<<<dim3(3072/32, 768/32),256,0,stream>>>(fc1_w + (size_t)i*768*3072, wf1T, 768, 3072);
    transpose_cvt_kernel<<<dim3(768/32, 3072/32),256,0,stream>>>(fc2_w + (size_t)i*3072*768, wf2T, 3072, 768);

    ln_kernel<<<1024,256,0,stream>>>(xbuf, ln1_g + i*768, ln1_b + i*768, nullptr, bufCs, 768, 1e-5f, 4096);
    int M;
    const ushort* qkvIn;
    int nWin, T, S;
    if (wsz > 0) {
      winpart_kernel<<<CDIV(25*196*96,256),256,0,stream>>>(bufCs, bufDs);
      qkvIn = bufDs; M = 4900; nWin = 25; T = 196; S = 14;
    } else {
      qkvIn = bufCs; M = 4096; nWin = 1; T = 4096; S = 64;
    }
    gemm_bf16_kernel<<<dim3(2304/128, CDIV(M,128)),256,0,stream>>>(
        qkvIn, wqT, qkv_b + i*2304, nullptr, nullptr, bufQEs, M, 2304, 768, 0);
    int relTot = nWin*12*T*S;
    relbias_kernel<<<CDIV(relTot,256),256,0,stream>>>(bufQEs, rel_h + i*127*64, rhB, nWin, T, S, 1);
    relbias_kernel<<<CDIV(relTot,256),256,0,stream>>>(bufQEs, rel_w + i*127*64, rwB, nWin, T, S, 0);
    if (wsz > 0)
      attn3_kernel<14><<<dim3(4,12,25),256,0,stream>>>(bufQEs, rhB, rwB, bufCs, 196);
    else
      attn4_kernel<<<dim3(64,12),256,0,stream>>>(bufQEs, rhB, rwB, bufCs);
    gemm_bf16_kernel<<<dim3(768/128, CDIV(M,128)),256,0,stream>>>(
        bufCs, wpT, proj_b + i*768, nullptr, bufD, nullptr, M, 768, 768, 0);
    if (wsz > 0)
      unpart_add_kernel<<<CDIV(4096*192,256),256,0,stream>>>(xbuf, bufD);
    else
      add4_kernel<<<CDIV(786432,256),256,0,stream>>>((float4*)xbuf, (const float4*)bufD, 786432);
    // MLP
    ln_kernel<<<1024,256,0,stream>>>(xbuf, ln2_g + i*768, ln2_b + i*768, nullptr, bufCs, 768, 1e-5f, 4096);
    gemm_bf16_kernel<<<dim3(3072/128, 4096/128),256,0,stream>>>(
        bufCs, wf1T, fc1_b + i*3072, nullptr, nullptr, bufQEs, 4096, 3072, 768, 1);
    // last layer: fused fp32 + bf16 output (bf16 feeds the neck)
    gemm_bf16_kernel<<<dim3(768/128, 4096/128),256,0,stream>>>(
        bufQEs, wf2T, fc2_b + i*768, xbuf, xbuf, (i==3) ? bufCs : nullptr, 4096, 768, 3072, 0);
  }

  // neck
  transpose_cvt_kernel<<<dim3(256/32, 768/32),256,0,stream>>>(nconv1, wnT, 768, 256);
  transpose_cvt_kernel<<<dim3(256/32, 2304/32),256,0,stream>>>(nconv2, wn2T, 2304, 256);
  gemm_bf16_kernel<<<dim3(256/128, 4096/128),256,0,stream>>>(
      bufCs, wnT, nullptr, nullptr, bufD, nullptr, 4096, 256, 768, 0);
  ln_kernel<<<1024,256,0,stream>>>(bufD, nln1_g, nln1_b, nullptr, bufCs, 256, 1e-6f, 4096);
  im2col3_kernel<<<CDIV(4096*288,256),256,0,stream>>>(bufCs, bufQEs);
  gemm_bf16_kernel<<<dim3(256/128, 4096/128),256,0,stream>>>(
      bufQEs, wn2T, nullptr, nullptr, bufD, nullptr, 4096, 256, 2304, 0);
  ln_kernel<<<1024,256,0,stream>>>(bufD, nln2_g, nln2_b, bufQE, nullptr, 256, 1e-6f, 4096);
  transpose_f32_kernel<<<dim3(256/32, 4096/32),256,0,stream>>>(bufQE, (float*)d_out, 4096, 256);
}

// Round 6
// 1920.885 us; speedup vs baseline: 7.8989x; 1.0463x over previous
//
#include <hip/hip_runtime.h>
#include <math.h>

#define CDIV(a,b) (((a)+(b)-1)/(b))

typedef __attribute__((ext_vector_type(8))) short short8v;   // 8 bf16 = 4 VGPRs
typedef __attribute__((ext_vector_type(4))) float float4v;

__device__ __forceinline__ ushort f2b(float f) {
  union { float f; unsigned u; } v; v.f = f;
  unsigned r = (v.u + 0x7fffu + ((v.u >> 16) & 1u)) >> 16;   // RNE
  return (ushort)r;
}
__device__ __forceinline__ float b2f(ushort h) {
  union { unsigned u; float f; } v; v.u = ((unsigned)h) << 16;
  return v.f;
}

// async global->LDS, 16B per lane; lds base must be wave-uniform (HW adds lane*16)
__device__ __forceinline__ void gload_lds16(const ushort* g, ushort* l) {
  __builtin_amdgcn_global_load_lds(
      (const __attribute__((address_space(1))) void*)g,
      (__attribute__((address_space(3))) void*)l, 16, 0, 0);
}

// ---------------------------------------------------------------- elementwise (vectorized)
__global__ __launch_bounds__(256) void copy4_kernel(float4* __restrict__ dst,
                                                    const float4* __restrict__ src, int n4) {
  int i = blockIdx.x*256 + threadIdx.x;
  if (i < n4) dst[i] = src[i];
}

__global__ __launch_bounds__(256) void add4_kernel(float4* __restrict__ x,
                                                   const float4* __restrict__ y, int n4) {
  int i = blockIdx.x*256 + threadIdx.x;
  if (i >= n4) return;
  float4 a = x[i], b = y[i];
  a.x += b.x; a.y += b.y; a.z += b.z; a.w += b.w;
  x[i] = a;
}

// ---------------------------------------------------------------- LayerNorm, one wave per row
__global__ __launch_bounds__(256) void ln_kernel(const float* __restrict__ in,
    const float* __restrict__ g, const float* __restrict__ b,
    float* __restrict__ outf, ushort* __restrict__ outb, int C, float eps, int nrows)
{
  int row = blockIdx.x*4 + (threadIdx.x >> 6);
  int lane = threadIdx.x & 63;
  if (row >= nrows) return;
  const float* rp = in + (size_t)row*C;
  float s = 0.f, s2 = 0.f;
  for (int c = lane; c < C; c += 64) { float v = rp[c]; s += v; s2 += v*v; }
  #pragma unroll
  for (int off = 32; off > 0; off >>= 1) { s += __shfl_xor(s, off); s2 += __shfl_xor(s2, off); }
  float mean = s / C;
  float var  = s2 / C - mean*mean;
  float inv  = rsqrtf(var + eps);
  for (int c = lane; c < C; c += 64) {
    float v = (rp[c]-mean)*inv*g[c] + b[c];
    if (outb) outb[(size_t)row*C + c] = f2b(v);
    else      outf[(size_t)row*C + c] = v;
  }
}

// ---------------------------------------------------------------- window partition (bf16, 8-wide)
__global__ __launch_bounds__(256) void winpart_kernel(const ushort* __restrict__ in,
                                                      ushort* __restrict__ out) {
  int i = blockIdx.x*256 + threadIdx.x;          // over 25*196*96 uint4 units
  if (i >= 25*196*96) return;
  int c8 = i % 96; int t = (i / 96) % 196; int b = i / (96*196);
  int wy = b / 5, wx = b % 5;
  int iy = t / 14, ix = t % 14;
  int h = wy*14 + iy, w = wx*14 + ix;
  uint4 v = {0u,0u,0u,0u};
  if (h < 64 && w < 64) v = *(const uint4*)(in + ((size_t)(h*64 + w))*768 + c8*8);
  *(uint4*)(out + (size_t)i*8) = v;
}

// window unpartition + residual add (float4)
__global__ __launch_bounds__(256) void unpart_add_kernel(float* __restrict__ x,
                                                         const float* __restrict__ p) {
  int i = blockIdx.x*256 + threadIdx.x;          // over 4096*192 float4 units
  if (i >= 4096*192) return;
  int c4 = i % 192; int hw = i / 192; int w = hw % 64; int h = hw / 64;
  int wy = h/14, iy = h%14, wx = w/14, ix = w%14;
  int b = wy*5 + wx; int t = iy*14 + ix;
  float4 a = *(const float4*)(x + (size_t)i*4);
  float4 r = *(const float4*)(p + ((size_t)(b*196 + t))*768 + c4*4);
  a.x += r.x; a.y += r.y; a.z += r.z; a.w += r.w;
  *(float4*)(x + (size_t)i*4) = a;
}

// ---------------------------------------------------------------- weight transpose+convert: in [K][N] f32 -> out [N][K] bf16
__global__ __launch_bounds__(256) void transpose_cvt_kernel(const float* __restrict__ in,
    ushort* __restrict__ out, int K, int N)
{
  __shared__ float t[32][33];
  int n0 = blockIdx.x*32, k0 = blockIdx.y*32;
  int cc = threadIdx.x & 31, rr = threadIdx.x >> 5;
  for (int r = rr; r < 32; r += 8) t[r][cc] = in[(size_t)(k0+r)*N + n0 + cc];
  __syncthreads();
  for (int r = rr; r < 32; r += 8) out[(size_t)(n0+r)*K + k0 + cc] = f2b(t[cc][r]);
}

// f32 transpose: in [R][Cc] -> out [Cc][R]  (for NHWC->NCHW)
__global__ __launch_bounds__(256) void transpose_f32_kernel(const float* __restrict__ in,
    float* __restrict__ out, int R, int Cc)
{
  __shared__ float t[32][33];
  int c0 = blockIdx.x*32, r0 = blockIdx.y*32;
  int cc = threadIdx.x & 31, rr = threadIdx.x >> 5;
  for (int r = rr; r < 32; r += 8) t[r][cc] = in[(size_t)(r0+r)*Cc + c0 + cc];
  __syncthreads();
  for (int r = rr; r < 32; r += 8) out[(size_t)(c0+r)*R + r0 + cc] = t[cc][r];
}

// ---------------------------------------------------------------- V transpose: qkv v-slice -> vt[wn][64 dim][strideV keys] bf16
__global__ __launch_bounds__(256) void vtrans_kernel(const ushort* __restrict__ qkv,
    ushort* __restrict__ vt, int T, int strideV)
{
  __shared__ ushort tile[64*72];
  int kt = blockIdx.x, wn = blockIdx.y;
  int win = wn / 12, n = wn - win*12;
  int tid = threadIdx.x;
  size_t tokBase = (size_t)win * T;
  int k0 = kt*64;
  #pragma unroll
  for (int it=0; it<2; ++it) {
    int id = tid + it*256;
    int r = id >> 3, ch = id & 7;
    int kk = k0 + r; if (kk >= T) kk = T-1;
    *(uint4*)(tile + r*72 + ch*8) =
      *(const uint4*)(qkv + (tokBase + kk)*2304 + 1536 + n*64 + ch*8);
  }
  __syncthreads();
  #pragma unroll
  for (int it=0; it<2; ++it) {
    int id = tid + it*256;
    int d = id & 63, kg = id >> 6;     // kg 0..7
    union { uint4 v; ushort u[8]; } o;
    #pragma unroll
    for (int j=0;j<8;++j) o.u[j] = tile[(kg*8+j)*72 + d];
    *(uint4*)(vt + ((size_t)wn*64 + d)*strideV + k0 + kg*8) = o.v;
  }
}

// ---------------------------------------------------------------- bf16 MFMA GEMM (m97 structure)
__global__ __launch_bounds__(256) void gemm_bf16_kernel(
    const ushort* __restrict__ A, const ushort* __restrict__ Bt,
    const float* __restrict__ bias, const float* __restrict__ res,
    float* __restrict__ Cf, ushort* __restrict__ Cb,
    int M, int N, int K, int act)
{
  __shared__ ushort Al[128*32];
  __shared__ ushort Bl[128*32];
  int tid = threadIdx.x;
  int lane = tid & 63, wave = tid >> 6;
  int wm = wave & 1, wn = wave >> 1;
  int l15 = lane & 15, lq = lane >> 4;
  int rowBase = blockIdx.y * 128, colBase = blockIdx.x * 128;
  float4v acc[4][4];
  #pragma unroll
  for (int i=0;i<4;++i)
    #pragma unroll
    for (int j=0;j<4;++j) acc[i][j] = (float4v){0.f,0.f,0.f,0.f};

  int rA0 = wave*16 + (lane>>2);
  int rA1 = rA0 + 64;
  int cs  = (lane&3) ^ ((lane>>3)&3);
  int gr0 = rowBase + rA0; if (gr0 >= M) gr0 = M-1;
  int gr1 = rowBase + rA1; if (gr1 >= M) gr1 = M-1;
  const ushort* aG0 = A  + (size_t)gr0*K + cs*8;
  const ushort* aG1 = A  + (size_t)gr1*K + cs*8;
  const ushort* bG0 = Bt + (size_t)(colBase + rA0)*K + cs*8;
  const ushort* bG1 = Bt + (size_t)(colBase + rA1)*K + cs*8;
  ushort* aL0 = Al + (wave*16)*32;
  ushort* aL1 = Al + (64 + wave*16)*32;
  ushort* bL0 = Bl + (wave*16)*32;
  ushort* bL1 = Bl + (64 + wave*16)*32;

  int sA = (l15 >> 1) & 3;
  int rdOff = ((lq ^ sA) << 3);

  for (int k0 = 0; k0 < K; k0 += 32) {
    __syncthreads();
    gload_lds16(aG0 + k0, aL0);
    gload_lds16(aG1 + k0, aL1);
    gload_lds16(bG0 + k0, bL0);
    gload_lds16(bG1 + k0, bL1);
    __syncthreads();
    short8v af[4], bf[4];
    #pragma unroll
    for (int mi=0; mi<4; ++mi)
      af[mi] = *(const short8v*)(Al + (wm*64 + mi*16 + l15)*32 + rdOff);
    #pragma unroll
    for (int ni=0; ni<4; ++ni)
      bf[ni] = *(const short8v*)(Bl + (wn*64 + ni*16 + l15)*32 + rdOff);
    #pragma unroll
    for (int mi=0; mi<4; ++mi)
      #pragma unroll
      for (int ni=0; ni<4; ++ni)
        acc[mi][ni] = __builtin_amdgcn_mfma_f32_16x16x32_bf16(af[mi], bf[ni], acc[mi][ni], 0, 0, 0);
  }
  #pragma unroll
  for (int mi=0; mi<4; ++mi) {
    int gr0e = rowBase + wm*64 + mi*16 + lq*4;
    #pragma unroll
    for (int ni=0; ni<4; ++ni) {
      int gc = colBase + wn*64 + ni*16 + l15;
      float bsv = bias ? bias[gc] : 0.f;
      #pragma unroll
      for (int r=0; r<4; ++r) {
        int gr = gr0e + r;
        if (gr < M) {
          float v = acc[mi][ni][r] + bsv;
          if (act) v = 0.5f*v*(1.f + erff(v*0.70710678118f));
          if (res) v += res[(size_t)gr*N + gc];
          if (Cf) Cf[(size_t)gr*N + gc] = v;
          if (Cb) Cb[(size_t)gr*N + gc] = f2b(v);
        }
      }
    }
  }
}

// ---------------------------------------------------------------- im2col for 3x3 SAME conv, bf16, 64x64x256
__global__ __launch_bounds__(256) void im2col3_kernel(const ushort* __restrict__ in,
                                                      ushort* __restrict__ out)
{
  int gid = blockIdx.x*256 + threadIdx.x;      // over 4096*288 uint4 units
  if (gid >= 4096*288) return;
  int u = gid % 288;  int p = gid / 288;
  int x = p & 63, y = p >> 6;
  int tap = u >> 5;
  int cu  = u & 31;
  int dy = tap / 3, dx = tap - dy*3;
  int yy = y + dy - 1, xx = x + dx - 1;
  uint4 v = {0u,0u,0u,0u};
  if (yy >= 0 && yy < 64 && xx >= 0 && xx < 64)
    v = *(const uint4*)(in + ((size_t)(yy*64 + xx))*256 + cu*8);
  *(uint4*)(out + (size_t)p*2304 + u*8) = v;
}

// ---------------------------------------------------------------- decomposed rel-pos bias (bf16 qkv in, bf16 out)
__global__ __launch_bounds__(256) void relbias_kernel(const ushort* __restrict__ qkv,
    const float* __restrict__ table, ushort* __restrict__ out,
    int nWin, int T, int S, int useH)
{
  int gid = blockIdx.x*256 + threadIdx.x;
  int total = nWin*12*T*S;
  if (gid >= total) return;
  int kk = gid % S; int r = gid / S;
  int t = r % T; int r2 = r / T; int n = r2 % 12; int b = r2 / 12;
  int coord = useH ? (t / S) : (t % S);
  const ushort* q = qkv + ((size_t)(b*T + t))*2304 + n*64;
  const float* tb = table + (size_t)(coord - kk + S - 1)*64;
  float s0=0.f, s1=0.f;
  #pragma unroll
  for (int d=0; d<64; d+=2) { s0 = fmaf(b2f(q[d]), tb[d], s0); s1 = fmaf(b2f(q[d+1]), tb[d+1], s1); }
  out[gid] = f2b(s0 + s1);
}

// ---------------------------------------------------------------- MFMA flash attention (windowed)
// Fixed-max softmax (M0=8 folded into RWl), deferred l-reduce, pre-transposed V.
template<int S>
__global__ __launch_bounds__(256) void attn3_kernel(
    const ushort* __restrict__ qkv, const ushort* __restrict__ rh,
    const ushort* __restrict__ rw, const ushort* __restrict__ vtw,
    ushort* __restrict__ outb, int T)
{
  constexpr int SP = (S + 15) & ~15;
  __shared__ ushort Ql[64*72];
  __shared__ ushort Kl[64*72];
  __shared__ ushort Vt[64*72];
  __shared__ ushort Pl[64*72];
  __shared__ ushort RHl[64*SP];
  __shared__ ushort RWl[64*SP];

  int qt = blockIdx.x, n = blockIdx.y, b = blockIdx.z;
  int wn = b*12 + n;
  int tid = threadIdx.x, lane = tid & 63, w = tid >> 6;
  int l15 = lane & 15, lq = lane >> 4;
  size_t tokBase = (size_t)b * T;
  int q0 = qt * 64;

  #pragma unroll
  for (int it = 0; it < 2; ++it) {
    int id = tid + it*256;
    int r = id >> 3, ch = id & 7;
    int qq = q0 + r; if (qq >= T) qq = T - 1;
    *(uint4*)(Ql + r*72 + ch*8) =
        *(const uint4*)(qkv + (tokBase + qq)*2304 + n*64 + ch*8);
  }
  for (int idx = tid; idx < 64*S; idx += 256) {
    int r = idx / S, c = idx - r*S;
    int qq = q0 + r; if (qq >= T) qq = T - 1;
    size_t base = ((size_t)(b*12 + n)*T + qq)*S;
    RHl[r*SP + c] = rh[base + c];
    RWl[r*SP + c] = f2b(b2f(rw[base + c]) - 8.0f);   // fold fixed max
  }
  __syncthreads();
  short8v aq0 = *(const short8v*)(Ql + (w*16 + l15)*72 + lq*8);
  short8v aq1 = *(const short8v*)(Ql + (w*16 + l15)*72 + 32 + lq*8);

  float lacc[4] = {0.f,0.f,0.f,0.f};
  float4v O[4];
  #pragma unroll
  for (int i=0;i<4;++i) O[i] = (float4v){0.f,0.f,0.f,0.f};

  int nkt = (T + 63) >> 6;
  for (int kt = 0; kt < nkt; ++kt) {
    int k0 = kt*64;
    __syncthreads();
    #pragma unroll
    for (int it=0; it<2; ++it) {
      int id = tid + it*256;
      int r = id >> 3, ch = id & 7;
      int kk = k0 + r; if (kk >= T) kk = T-1;
      *(uint4*)(Kl + r*72 + ch*8) =
        *(const uint4*)(qkv + (tokBase + kk)*2304 + 768 + n*64 + ch*8);
      *(uint4*)(Vt + r*72 + ch*8) =
        *(const uint4*)(vtw + ((size_t)wn*64 + r)*256 + k0 + ch*8);
    }
    __syncthreads();

    float4v Sv[4];
    #pragma unroll
    for (int ni=0; ni<4; ++ni) {
      short8v bk0 = *(const short8v*)(Kl + (ni*16 + l15)*72 + lq*8);
      short8v bk1 = *(const short8v*)(Kl + (ni*16 + l15)*72 + 32 + lq*8);
      float4v s = (float4v){0.f,0.f,0.f,0.f};
      s = __builtin_amdgcn_mfma_f32_16x16x32_bf16(aq0, bk0, s, 0,0,0);
      s = __builtin_amdgcn_mfma_f32_16x16x32_bf16(aq1, bk1, s, 0,0,0);
      Sv[ni] = s;
    }

    #pragma unroll
    for (int r=0;r<4;++r) {
      int qlrow = w*16 + lq*4 + r;
      #pragma unroll
      for (int ni=0;ni<4;++ni) {
        int key = k0 + ni*16 + l15;
        int kcl = key < T ? key : 0;
        int kh = kcl / S, kw = kcl - kh*S;
        float sc = key < T
          ? fmaf(Sv[ni][r], 0.125f, b2f(RHl[qlrow*SP+kh]) + b2f(RWl[qlrow*SP+kw]))
          : -1e30f;
        float pv = __expf(sc);
        lacc[r] += pv;
        union { float f; unsigned u; } cv; cv.f = pv;
        Pl[qlrow*72 + ni*16 + l15] = (ushort)((cv.u + 0x8000u) >> 16);
      }
    }

    short8v ap0 = *(const short8v*)(Pl + (w*16 + l15)*72 + lq*8);
    short8v ap1 = *(const short8v*)(Pl + (w*16 + l15)*72 + 32 + lq*8);
    #pragma unroll
    for (int ni=0;ni<4;++ni) {
      short8v bv0 = *(const short8v*)(Vt + (ni*16 + l15)*72 + lq*8);
      short8v bv1 = *(const short8v*)(Vt + (ni*16 + l15)*72 + 32 + lq*8);
      O[ni] = __builtin_amdgcn_mfma_f32_16x16x32_bf16(ap0, bv0, O[ni], 0,0,0);
      O[ni] = __builtin_amdgcn_mfma_f32_16x16x32_bf16(ap1, bv1, O[ni], 0,0,0);
    }
  }

  #pragma unroll
  for (int r=0;r<4;++r) {
    int qlrow = w*16 + lq*4 + r;
    int qg = q0 + qlrow;
    float ls = lacc[r];
    #pragma unroll
    for (int off=1; off<16; off<<=1) ls += __shfl_xor(ls, off);
    if (qg < T) {
      float inv = 1.f / ls;
      #pragma unroll
      for (int ni=0;ni<4;++ni)
        outb[(tokBase + qg)*768 + n*64 + ni*16 + l15] = f2b(O[ni][r]*inv);
    }
  }
}

// ---------------------------------------------------------------- specialized global flash attention (T=4096, S=64)
// kh = kt (uniform per tile), kw fixed per lane; fixed-max softmax, deferred l-reduce.
__global__ __launch_bounds__(256) void attn4_kernel(
    const ushort* __restrict__ qkv, const ushort* __restrict__ rh,
    const ushort* __restrict__ rw, const ushort* __restrict__ vtg,
    ushort* __restrict__ outb)
{
  const int T = 4096;
  __shared__ ushort Ql[64*72];
  __shared__ ushort Kl[64*72];
  __shared__ ushort Vt[64*72];
  __shared__ ushort Pl[64*72];
  __shared__ ushort RHl[64*64];   // [qrow][kh]

  int qt = blockIdx.x, n = blockIdx.y;
  int tid = threadIdx.x, lane = tid & 63, w = tid >> 6;
  int l15 = lane & 15, lq = lane >> 4;
  int q0 = qt * 64;

  #pragma unroll
  for (int it = 0; it < 2; ++it) {
    int id = tid + it*256;
    int r = id >> 3, ch = id & 7;
    *(uint4*)(Ql + r*72 + ch*8) =
        *(const uint4*)(qkv + (size_t)(q0 + r)*2304 + n*64 + ch*8);
    *(uint4*)(RHl + r*64 + ch*8) =
        *(const uint4*)(rh + ((size_t)n*T + q0 + r)*64 + ch*8);
  }
  // preload this lane's rw values (kw fixed across tiles), fold fixed max -8
  float rwp[4][4];
  #pragma unroll
  for (int r=0;r<4;++r)
    #pragma unroll
    for (int ni=0;ni<4;++ni)
      rwp[r][ni] = b2f(rw[((size_t)n*T + q0 + w*16 + lq*4 + r)*64 + ni*16 + l15]) - 8.0f;

  __syncthreads();
  short8v aq0 = *(const short8v*)(Ql + (w*16 + l15)*72 + lq*8);
  short8v aq1 = *(const short8v*)(Ql + (w*16 + l15)*72 + 32 + lq*8);

  float lacc[4] = {0.f,0.f,0.f,0.f};
  float4v O[4];
  #pragma unroll
  for (int i=0;i<4;++i) O[i] = (float4v){0.f,0.f,0.f,0.f};

  const ushort* vbase = vtg + (size_t)n*64*4096;   // [dim][key]

  for (int kt = 0; kt < 64; ++kt) {
    int k0 = kt*64;
    __syncthreads();
    #pragma unroll
    for (int it=0; it<2; ++it) {
      int id = tid + it*256;
      int r = id >> 3, ch = id & 7;
      *(uint4*)(Kl + r*72 + ch*8) =
        *(const uint4*)(qkv + (size_t)(k0 + r)*2304 + 768 + n*64 + ch*8);
      *(uint4*)(Vt + r*72 + ch*8) =
        *(const uint4*)(vbase + (size_t)r*4096 + k0 + ch*8);
    }
    __syncthreads();

    float4v Sv[4];
    #pragma unroll
    for (int ni=0; ni<4; ++ni) {
      short8v bk0 = *(const short8v*)(Kl + (ni*16 + l15)*72 + lq*8);
      short8v bk1 = *(const short8v*)(Kl + (ni*16 + l15)*72 + 32 + lq*8);
      float4v s = (float4v){0.f,0.f,0.f,0.f};
      s = __builtin_amdgcn_mfma_f32_16x16x32_bf16(aq0, bk0, s, 0,0,0);
      s = __builtin_amdgcn_mfma_f32_16x16x32_bf16(aq1, bk1, s, 0,0,0);
      Sv[ni] = s;
    }

    #pragma unroll
    for (int r=0;r<4;++r) {
      int qlrow = w*16 + lq*4 + r;
      float rhv = b2f(RHl[qlrow*64 + kt]);   // broadcast read
      #pragma unroll
      for (int ni=0;ni<4;++ni) {
        float pv = __expf(fmaf(Sv[ni][r], 0.125f, rhv + rwp[r][ni]));
        lacc[r] += pv;
        union { float f; unsigned u; } cv; cv.f = pv;
        Pl[qlrow*72 + ni*16 + l15] = (ushort)((cv.u + 0x8000u) >> 16);
      }
    }

    // P rows are wave-private -> no barrier
    short8v ap0 = *(const short8v*)(Pl + (w*16 + l15)*72 + lq*8);
    short8v ap1 = *(const short8v*)(Pl + (w*16 + l15)*72 + 32 + lq*8);
    #pragma unroll
    for (int ni=0;ni<4;++ni) {
      short8v bv0 = *(const short8v*)(Vt + (ni*16 + l15)*72 + lq*8);
      short8v bv1 = *(const short8v*)(Vt + (ni*16 + l15)*72 + 32 + lq*8);
      O[ni] = __builtin_amdgcn_mfma_f32_16x16x32_bf16(ap0, bv0, O[ni], 0,0,0);
      O[ni] = __builtin_amdgcn_mfma_f32_16x16x32_bf16(ap1, bv1, O[ni], 0,0,0);
    }
  }

  #pragma unroll
  for (int r=0;r<4;++r) {
    int qg = q0 + w*16 + lq*4 + r;
    float ls = lacc[r];
    #pragma unroll
    for (int off=1; off<16; off<<=1) ls += __shfl_xor(ls, off);
    float inv = 1.f / ls;
    #pragma unroll
    for (int ni=0;ni<4;++ni)
      outb[(size_t)qg*768 + n*64 + ni*16 + l15] = f2b(O[ni][r]*inv);
  }
}

// ================================================================ launch
extern "C" void kernel_launch(void* const* d_in, const int* in_sizes, int n_in,
                              void* d_out, int out_size, void* d_ws, size_t ws_size,
                              hipStream_t stream)
{
  const float* x_in   = (const float*)d_in[0];
  const float* ln1_g  = (const float*)d_in[1];
  const float* ln1_b  = (const float*)d_in[2];
  const float* qkv_w  = (const float*)d_in[3];
  const float* qkv_b  = (const float*)d_in[4];
  const float* proj_w = (const float*)d_in[5];
  const float* proj_b = (const float*)d_in[6];
  const float* rel_h  = (const float*)d_in[7];
  const float* rel_w  = (const float*)d_in[8];
  const float* ln2_g  = (const float*)d_in[9];
  const float* ln2_b  = (const float*)d_in[10];
  const float* fc1_w  = (const float*)d_in[11];
  const float* fc1_b  = (const float*)d_in[12];
  const float* fc2_w  = (const float*)d_in[13];
  const float* fc2_b  = (const float*)d_in[14];
  const float* nconv1 = (const float*)d_in[15];
  const float* nln1_g = (const float*)d_in[16];
  const float* nln1_b = (const float*)d_in[17];
  const float* nconv2 = (const float*)d_in[18];
  const float* nln2_g = (const float*)d_in[19];
  const float* nln2_b = (const float*)d_in[20];

  // workspace layout (floats); total ~108.9 MB
  float*  ws     = (float*)d_ws;
  float*  xbuf   = ws;                                   // 3,145,728 fl
  ushort* bufCs  = (ushort*)(xbuf + 3145728);            // 3,763,200 sh
  float*  bufD   = xbuf + 3145728 + 1881600;             // 3,763,200 fl
  float*  bufQE  = bufD + 3763200;                       // 11,289,600 fl
  ushort* bufQEs = (ushort*)bufQE;
  ushort* rhB    = (ushort*)(bufQE + 11289600);          // 3,145,728 sh
  ushort* rwB    = rhB + 3145728;                        // 3,145,728 sh
  ushort* wqT    = rwB + 3145728;                        // 1,769,472 sh
  ushort* wpT    = wqT + 1769472;                        //   589,824 sh
  ushort* wf1T   = wpT + 589824;                         // 2,359,296 sh
  ushort* wf2T   = wf1T + 2359296;                       // 2,359,296 sh
  ushort* wnT    = wf2T + 2359296;                       //   196,608 sh
  ushort* wn2T   = wnT + 196608;                         //   589,824 sh
  ushort* bufDs  = (ushort*)bufD;                        // also hosts VT during attention

  copy4_kernel<<<CDIV(786432,256),256,0,stream>>>((float4*)xbuf, (const float4*)x_in, 786432);

  for (int i = 0; i < 4; ++i) {
    int wsz = (i < 3) ? 14 : 0;
    transpose_cvt_kernel<<<dim3(2304/32, 768/32),256,0,stream>>>(qkv_w + (size_t)i*768*2304, wqT, 768, 2304);
    transpose_cvt_kernel<<<dim3(768/32,  768/32),256,0,stream>>>(proj_w + (size_t)i*768*768,  wpT, 768, 768);
    transpose_cvt_kernel<<<dim3(3072/32, 768/32),256,0,stream>>>(fc1_w + (size_t)i*768*3072, wf1T, 768, 3072);
    transpose_cvt_kernel<<<dim3(768/32, 3072/32),256,0,stream>>>(fc2_w + (size_t)i*3072*768, wf2T, 3072, 768);

    ln_kernel<<<1024,256,0,stream>>>(xbuf, ln1_g + i*768, ln1_b + i*768, nullptr, bufCs, 768, 1e-5f, 4096);
    int M;
    const ushort* qkvIn;
    int nWin, T, S;
    if (wsz > 0) {
      winpart_kernel<<<CDIV(25*196*96,256),256,0,stream>>>(bufCs, bufDs);
      qkvIn = bufDs; M = 4900; nWin = 25; T = 196; S = 14;
    } else {
      qkvIn = bufCs; M = 4096; nWin = 1; T = 4096; S = 64;
    }
    gemm_bf16_kernel<<<dim3(2304/128, CDIV(M,128)),256,0,stream>>>(
        qkvIn, wqT, qkv_b + i*2304, nullptr, nullptr, bufQEs, M, 2304, 768, 0);
    int relTot = nWin*12*T*S;
    relbias_kernel<<<CDIV(relTot,256),256,0,stream>>>(bufQEs, rel_h + i*127*64, rhB, nWin, T, S, 1);
    relbias_kernel<<<CDIV(relTot,256),256,0,stream>>>(bufQEs, rel_w + i*127*64, rwB, nWin, T, S, 0);
    if (wsz > 0) {
      vtrans_kernel<<<dim3(4, 300),256,0,stream>>>(bufQEs, bufDs, 196, 256);
      attn3_kernel<14><<<dim3(4,12,25),256,0,stream>>>(bufQEs, rhB, rwB, bufDs, bufCs, 196);
    } else {
      vtrans_kernel<<<dim3(64, 12),256,0,stream>>>(bufQEs, bufDs, 4096, 4096);
      attn4_kernel<<<dim3(64,12),256,0,stream>>>(bufQEs, rhB, rwB, bufDs, bufCs);
    }
    gemm_bf16_kernel<<<dim3(768/128, CDIV(M,128)),256,0,stream>>>(
        bufCs, wpT, proj_b + i*768, nullptr, bufD, nullptr, M, 768, 768, 0);
    if (wsz > 0)
      unpart_add_kernel<<<CDIV(4096*192,256),256,0,stream>>>(xbuf, bufD);
    else
      add4_kernel<<<CDIV(786432,256),256,0,stream>>>((float4*)xbuf, (const float4*)bufD, 786432);
    // MLP
    ln_kernel<<<1024,256,0,stream>>>(xbuf, ln2_g + i*768, ln2_b + i*768, nullptr, bufCs, 768, 1e-5f, 4096);
    gemm_bf16_kernel<<<dim3(3072/128, 4096/128),256,0,stream>>>(
        bufCs, wf1T, fc1_b + i*3072, nullptr, nullptr, bufQEs, 4096, 3072, 768, 1);
    gemm_bf16_kernel<<<dim3(768/128, 4096/128),256,0,stream>>>(
        bufQEs, wf2T, fc2_b + i*768, xbuf, xbuf, (i==3) ? bufCs : nullptr, 4096, 768, 3072, 0);
  }

  // neck
  transpose_cvt_kernel<<<dim3(256/32, 768/32),256,0,stream>>>(nconv1, wnT, 768, 256);
  transpose_cvt_kernel<<<dim3(256/32, 2304/32),256,0,stream>>>(nconv2, wn2T, 2304, 256);
  gemm_bf16_kernel<<<dim3(256/128, 4096/128),256,0,stream>>>(
      bufCs, wnT, nullptr, nullptr, bufD, nullptr, 4096, 256, 768, 0);
  ln_kernel<<<1024,256,0,stream>>>(bufD, nln1_g, nln1_b, nullptr, bufCs, 256, 1e-6f, 4096);
  im2col3_kernel<<<CDIV(4096*288,256),256,0,stream>>>(bufCs, bufQEs);
  gemm_bf16_kernel<<<dim3(256/128, 4096/128),256,0,stream>>>(
      bufQEs, wn2T, nullptr, nullptr, bufD, nullptr, 4096, 256, 2304, 0);
  ln_kernel<<<1024,256,0,stream>>>(bufD, nln2_g, nln2_b, bufQE, nullptr, 256, 1e-6f, 4096);
  transpose_f32_kernel<<<dim3(256/32, 4096/32),256,0,stream>>>(bufQE, (float*)d_out, 4096, 256);
}